// Round 7
// baseline (550.411 us; speedup 1.0000x reference)
//
#include <hip/hip_runtime.h>

#define NN   50000
#define EE   800000
#define MPAD 50048   // 391 * 128
#define NBLK ((NN + 255) / 256)   // 196

typedef __bf16 bf16x8 __attribute__((ext_vector_type(8)));
typedef float  vfloat4 __attribute__((ext_vector_type(4)));
typedef short  vshort4 __attribute__((ext_vector_type(4)));
typedef short  vshort8 __attribute__((ext_vector_type(8)));

__device__ __forceinline__ short f2bf(float f) {
  union { float f; unsigned u; } v; v.f = f;
  unsigned r = v.u + 0x7FFFu + ((v.u >> 16) & 1u);   // RNE
  return (short)(r >> 16);
}
__device__ __forceinline__ float bf2f(short h) {
  union { unsigned u; float f; } v; v.u = ((unsigned)(unsigned short)h) << 16;
  return v.f;
}

__device__ __forceinline__ void load_lds16(const short* g, short* l) {
  __builtin_amdgcn_global_load_lds(
      (__attribute__((address_space(1))) void*)(void*)g,
      (__attribute__((address_space(3))) void*)(void*)l, 16, 0, 0);
}

// ---------------- edge dtype detect (int64 vs int32) ----------------
__global__ __launch_bounds__(256) void detect_kernel(const unsigned* __restrict__ e,
                                                     int* __restrict__ flag) {
  unsigned v = 0;
  for (int i = threadIdx.x; i < 2048; i += 256) v |= e[2 * i + 1];
  for (int o = 32; o; o >>= 1) v |= (unsigned)__shfl_down((int)v, o, 64);
  __shared__ unsigned r[4];
  if ((threadIdx.x & 63) == 0) r[threadIdx.x >> 6] = v;
  __syncthreads();
  if (threadIdx.x == 0) flag[0] = ((r[0] | r[1] | r[2] | r[3]) == 0) ? 1 : 0;
}

// ---------------- CSR build ----------------
__global__ __launch_bounds__(256) void degree_kernel(const void* __restrict__ edges,
                                                     const int* __restrict__ flag,
                                                     int* __restrict__ deg) {
  int e = blockIdx.x * 256 + threadIdx.x;
  if (e >= EE) return;
  int d = flag[0] ? (int)((const long long*)edges)[EE + e] : ((const int*)edges)[EE + e];
  atomicAdd(&deg[d], 1);
}

__global__ __launch_bounds__(256) void scan_local(const int* __restrict__ deg,
                                                  int* __restrict__ iscan,
                                                  int* __restrict__ bsum) {
  __shared__ int tmp[256];
  int t = threadIdx.x;
  int i = blockIdx.x * 256 + t;
  int v = (i < NN) ? deg[i] : 0;
  tmp[t] = v;
  __syncthreads();
  int acc = v;
  for (int d = 1; d < 256; d <<= 1) {
    int u = (t >= d) ? tmp[t - d] : 0;
    __syncthreads();
    acc += u;
    tmp[t] = acc;
    __syncthreads();
  }
  if (i < NN) iscan[i] = acc - v;     // exclusive within block
  if (t == 255) bsum[blockIdx.x] = acc;
}

__global__ __launch_bounds__(256) void scan_apply(const int* __restrict__ iscan,
                                                  const int* __restrict__ bsum,
                                                  int* __restrict__ offs,
                                                  int* __restrict__ cursor) {
  __shared__ int sh[256];
  int t = threadIdx.x;
  int v = (t < NBLK) ? bsum[t] : 0;
  sh[t] = (t < (int)blockIdx.x) ? v : 0;
  __syncthreads();
  for (int d = 128; d; d >>= 1) { if (t < d) sh[t] += sh[t + d]; __syncthreads(); }
  int base = sh[0];
  __syncthreads();
  sh[t] = v;
  __syncthreads();
  for (int d = 128; d; d >>= 1) { if (t < d) sh[t] += sh[t + d]; __syncthreads(); }
  int total = sh[0];
  int i = blockIdx.x * 256 + t;
  if (i < NN) { int off = iscan[i] + base; offs[i] = off; cursor[i] = off; }
  if (blockIdx.x == gridDim.x - 1 && t == 0) offs[NN] = total;
}

__global__ __launch_bounds__(256) void fill_kernel(const void* __restrict__ edges,
                                                   const int* __restrict__ flag,
                                                   int* __restrict__ cursor,
                                                   int* __restrict__ csr) {
  int e = blockIdx.x * 256 + threadIdx.x;
  if (e >= EE) return;
  int sv, dv;
  if (flag[0]) {
    sv = (int)((const long long*)edges)[e];
    dv = (int)((const long long*)edges)[EE + e];
  } else {
    sv = ((const int*)edges)[e];
    dv = ((const int*)edges)[EE + e];
  }
  int p = atomicAdd(&cursor[dv], 1);
  __builtin_nontemporal_store(sv, &csr[p]);   // avoid write-allocate ping-pong
}

// ---------------- x -> bf16 cast (NN x 128) ----------------
__global__ __launch_bounds__(256) void xcast_kernel(const float* __restrict__ x,
                                                    short* __restrict__ xbf) {
  int i = blockIdx.x * 256 + threadIdx.x;   // one per 8 elems
  if (i >= NN * 128 / 8) return;
  vfloat4 v0 = *(const vfloat4*)(x + (size_t)i * 8);
  vfloat4 v1 = *(const vfloat4*)(x + (size_t)i * 8 + 4);
  vshort8 o;
  o[0] = f2bf(v0.x); o[1] = f2bf(v0.y); o[2] = f2bf(v0.z); o[3] = f2bf(v0.w);
  o[4] = f2bf(v1.x); o[5] = f2bf(v1.y); o[6] = f2bf(v1.z); o[7] = f2bf(v1.w);
  *(vshort8*)(xbf + (size_t)i * 8) = o;
}

// ---------------- all weight preps in one launch ----------------
__global__ __launch_bounds__(256) void prep_all(
    const float* __restrict__ Wl1, const float* __restrict__ Wr1,
    const float* __restrict__ W1,  const float* __restrict__ W2,
    const float* __restrict__ Wl2, const float* __restrict__ Wr2,
    const float* __restrict__ W3,  const float* __restrict__ W4,
    short* __restrict__ wc1T, short* __restrict__ w1T, short* __restrict__ w2T,
    short* __restrict__ wlr2T, short* __restrict__ w3T, short* __restrict__ w4T) {
  int b = blockIdx.x;
  if (b >= 1280 && b < 1536) {
    // wlr2T: col-split concat [Wl2 | Wr2], 256 cols x 256 k
    int idx = (b - 1280) * 256 + threadIdx.x;
    int n = idx >> 8, k = idx & 255;
    float v = (n < 128) ? Wl2[(size_t)k * 128 + n] : Wr2[(size_t)k * 128 + (n - 128)];
    wlr2T[idx] = f2bf(v);
    return;
  }
  const float *s0, *s1; short* dst; int K0, logK, Nc, base;
  if      (b <  256) { s0=Wl1; s1=Wr1; dst=wc1T; K0=128; logK=8; Nc=256; base=0;    }
  else if (b <  768) { s0=W1;  s1=W1;  dst=w1T;  K0=256; logK=8; Nc=512; base=256;  }
  else if (b < 1280) { s0=W2;  s1=W2;  dst=w2T;  K0=512; logK=9; Nc=256; base=768;  }
  else if (b < 1664) { s0=W3;  s1=W3;  dst=w3T;  K0=128; logK=7; Nc=256; base=1536; }
  else               { s0=W4;  s1=W4;  dst=w4T;  K0=256; logK=8; Nc=128; base=1664; }
  int idx = (b - base) * 256 + threadIdx.x;
  int n = idx >> logK, k = idx & ((1 << logK) - 1);
  float v = (k < K0) ? s0[(size_t)k * Nc + n] : s1[(size_t)(k - K0) * Nc + n];
  dst[idx] = f2bf(v);
}

// cbias[256] = [0 x128 | bl2]
__global__ __launch_bounds__(256) void prep_bias(const float* __restrict__ bl2,
                                                 float* __restrict__ cbias) {
  int t = threadIdx.x;
  cbias[t] = (t < 128) ? 0.f : bl2[t - 128];
}

// ---------------- mean aggregation over 128-elem bf16 rows (256 B) ----------
// 1 wave/node; 4 lane-groups of 16. All __shfl with FULL wave active (R4
// lesson). CONCAT=1 also copies node's own row into dst second half.
template<int CONCAT>
__global__ __launch_bounds__(256) void agg_mean(const short* __restrict__ src,
                                                const int* __restrict__ offs,
                                                const int* __restrict__ csr,
                                                short* __restrict__ dst) {
  int node = blockIdx.x * 4 + (threadIdx.x >> 6);
  int lane = threadIdx.x & 63;
  if (node >= MPAD) return;
  short* row = dst + (size_t)node * (CONCAT ? 256 : 128);
  if (node >= NN) {
    if (CONCAT) *(vshort4*)(row + lane * 4) = (vshort4){0, 0, 0, 0};
    else if (lane < 32) *(vshort4*)(row + lane * 4) = (vshort4){0, 0, 0, 0};
    return;
  }
  int g = lane >> 4, sub = lane & 15;
  int e0 = offs[node], e1 = offs[node + 1];
  float a0[8] = {0, 0, 0, 0, 0, 0, 0, 0};
  float a1[8] = {0, 0, 0, 0, 0, 0, 0, 0};
  int e = e0;
  while (e < e1) {                         // wave-uniform
    int cnt = e1 - e; if (cnt > 64) cnt = 64;
    int myidx = (lane < cnt) ? csr[e + lane] : 0;
    for (int i = 0; i < cnt; i += 8) {     // wave-uniform bound
      int p0 = g + i;
      int p1 = g + i + 4;
      int s0 = __shfl(myidx, p0, 64);      // full wave active
      int s1 = __shfl(myidx, p1, 64);
      if (p0 < cnt) {
        vshort8 v0 = *(const vshort8*)(src + (size_t)s0 * 128 + sub * 8);
#pragma unroll
        for (int j = 0; j < 8; j++) a0[j] += bf2f(v0[j]);
      }
      if (p1 < cnt) {
        vshort8 v1 = *(const vshort8*)(src + (size_t)s1 * 128 + sub * 8);
#pragma unroll
        for (int j = 0; j < 8; j++) a1[j] += bf2f(v1[j]);
      }
    }
    e += cnt;
  }
#pragma unroll
  for (int j = 0; j < 8; j++) {
    a0[j] += a1[j];
    a0[j] += __shfl_down(a0[j], 32, 64);
    a0[j] += __shfl_down(a0[j], 16, 64);
  }
  float inv = (e1 > e0) ? 1.f / (float)(e1 - e0) : 0.f;
  if (g == 0) {
    vshort8 o;
#pragma unroll
    for (int j = 0; j < 8; j++) o[j] = f2bf(a0[j] * inv);
    *(vshort8*)(row + sub * 8) = o;
  } else if (CONCAT && g == 1) {
    *(vshort8*)(row + 128 + sub * 8) = *(const vshort8*)(src + (size_t)node * 128 + sub * 8);
  }
}

// ---------------- h_d = r2 + a2 (bf16), fused LN stats ----------------
__global__ __launch_bounds__(256) void add_stats(const short* __restrict__ r2,
                                                 const short* __restrict__ a2,
                                                 short* __restrict__ h_d,
                                                 float* __restrict__ statsOut) {
  int i = blockIdx.x * 256 + threadIdx.x;   // per 8 elems
  const int tot8 = MPAD * 128 / 8, real8 = NN * 128 / 8;
  float s = 0.f, s2 = 0.f;
  if (i < tot8) {
    if (i >= real8) {
      *(vshort8*)(h_d + (size_t)i * 8) = (vshort8){0,0,0,0,0,0,0,0};
    } else {
      vshort8 rv = *(const vshort8*)(r2 + (size_t)i * 8);
      vshort8 av = *(const vshort8*)(a2 + (size_t)i * 8);
      vshort8 o;
#pragma unroll
      for (int j = 0; j < 8; j++) {
        float v = bf2f(rv[j]) + bf2f(av[j]);
        s += v; s2 += v * v;
        o[j] = f2bf(v);
      }
      *(vshort8*)(h_d + (size_t)i * 8) = o;
    }
  }
  int lane = threadIdx.x & 63, wave = threadIdx.x >> 6;
  for (int o2 = 32; o2; o2 >>= 1) {
    s  += __shfl_down(s,  o2, 64);
    s2 += __shfl_down(s2, o2, 64);
  }
  __shared__ float ps[8];
  if (lane == 0) { ps[wave] = s; ps[wave + 4] = s2; }
  __syncthreads();
  if (threadIdx.x == 0) {
    atomicAdd(&statsOut[0], ps[0] + ps[1] + ps[2] + ps[3]);
    atomicAdd(&statsOut[1], ps[4] + ps[5] + ps[6] + ps[7]);
  }
}

// ---------------- graph LayerNorm apply (bf16 in) ----------------
__global__ __launch_bounds__(256) void ln_apply(const short* __restrict__ h,
                                                const float* __restrict__ stats,
                                                const float* __restrict__ w,
                                                const float* __restrict__ b,
                                                short* __restrict__ out,
                                                int realElems, int totElems, int F,
                                                float invCount) {
  int base = (blockIdx.x * blockDim.x + threadIdx.x) * 4;
  if (base >= totElems) return;
  if (base >= realElems) { *(vshort4*)(out + base) = (vshort4){0,0,0,0}; return; }
  float mu  = stats[0] * invCount;
  float var = stats[1] * invCount - mu * mu;
  float rs  = rsqrtf(var + 1e-5f);
  int col = base % F;
  vshort4 hv = *(const vshort4*)(h + base);
  vshort4 o;
  o.x = f2bf(fmaxf((bf2f(hv.x) - mu) * rs * w[col]     + b[col],     0.f));
  o.y = f2bf(fmaxf((bf2f(hv.y) - mu) * rs * w[col + 1] + b[col + 1], 0.f));
  o.z = f2bf(fmaxf((bf2f(hv.z) - mu) * rs * w[col + 2] + b[col + 2], 0.f));
  o.w = f2bf(fmaxf((bf2f(hv.w) - mu) * rs * w[col + 3] + b[col + 3], 0.f));
  *(vshort4*)(out + base) = o;
}

// ---------------- GEMM: C = A(MxK) * BT(NcxK)^T + bias --------------------
// BK=64, XOR-swizzled LDS (conflict-free ds_read_b128), SWAPPED mfma operands
// so each lane's acc reg holds 4 consecutive cols -> vectorized epilogue
// (16 x 8B stores instead of 64 scalar). SPLIT=1: Nc=256, cols<128 -> Cb,
// cols>=128 -> Cb2 (both stride 128). STATS: graph-LN sum/sumsq, rows<Mreal.
template<int RELU, int OUTBF, int BOUND, int STATS, int SPLIT>
__global__ __launch_bounds__(256) void gemm_bt(const short* __restrict__ A,
                                               const short* __restrict__ BT,
                                               const float* __restrict__ bias,
                                               float* __restrict__ Cf,
                                               short* __restrict__ Cb,
                                               short* __restrict__ Cb2,
                                               float* __restrict__ statsOut,
                                               int Nc, int K, int Mreal) {
  __shared__ short lsA[128 * 64];   // 16 KB, row-major 64 k-elems, XOR-swizzled
  __shared__ short lsB[128 * 64];
  const int tid  = threadIdx.x;
  const int lane = tid & 63;
  const int wave = tid >> 6;
  const int wr   = (wave >> 1) << 6;
  const int wc   = (wave & 1) << 6;
  const int row0 = blockIdx.y << 7;
  const int col0 = blockIdx.x << 7;
  const int r16  = lane & 15;
  const int quad = lane >> 4;
  const int srow   = lane >> 3;          // 0..7 row within 8-row staging seg
  const int schunk = lane & 7;           // 16B chunk slot within row
  const int sxoff  = ((schunk ^ srow) << 3);  // XOR-permuted source k-offset

  vfloat4 acc[4][4];
#pragma unroll
  for (int i = 0; i < 4; i++)
#pragma unroll
    for (int j = 0; j < 4; j++) acc[i][j] = (vfloat4){0.f, 0.f, 0.f, 0.f};

  for (int k0 = 0; k0 < K; k0 += 64) {
    __syncthreads();
#pragma unroll
    for (int t = 0; t < 4; t++) {
      int seg  = (wave << 2) + t;        // 0..15, 8 rows each
      int trow = (seg << 3) + srow;
      load_lds16(A  + (size_t)(row0 + trow) * K + k0 + sxoff, lsA + (seg << 9) + lane * 8);
      load_lds16(BT + (size_t)(col0 + trow) * K + k0 + sxoff, lsB + (seg << 9) + lane * 8);
    }
    __syncthreads();
#pragma unroll
    for (int kk = 0; kk < 64; kk += 32) {
      int kf8 = (kk >> 3) + quad;        // global 16B-chunk index
      bf16x8 af[4], bfr[4];
#pragma unroll
      for (int i = 0; i < 4; i++) {
        int r = wr + (i << 4) + r16;
        af[i] = *(const bf16x8*)(lsA + (r << 6) + ((kf8 ^ (r & 7)) << 3));
      }
#pragma unroll
      for (int j = 0; j < 4; j++) {
        int r = wc + (j << 4) + r16;
        bfr[j] = *(const bf16x8*)(lsB + (r << 6) + ((kf8 ^ (r & 7)) << 3));
      }
#pragma unroll
      for (int i = 0; i < 4; i++)
#pragma unroll
        for (int j = 0; j < 4; j++)
          acc[i][j] = __builtin_amdgcn_mfma_f32_16x16x32_bf16(bfr[j], af[i], acc[i][j], 0, 0, 0);
    }
  }

  // epilogue: row = row0+wr+i*16+r16 (per-lane), col = col0+wc+j*16+quad*4+p
  float s = 0.f, s2 = 0.f;
#pragma unroll
  for (int i = 0; i < 4; i++) {
    int gr = row0 + wr + (i << 4) + r16;
    if (BOUND && gr >= Mreal) continue;
#pragma unroll
    for (int j = 0; j < 4; j++) {
      int gc = col0 + wc + (j << 4) + (quad << 2);
      vfloat4 bv = *(const vfloat4*)(bias + gc);
      vfloat4 v;
#pragma unroll
      for (int p = 0; p < 4; p++) {
        float t = acc[i][j][p] + bv[p];
        if (STATS) { s += t; s2 += t * t; }
        if (RELU) t = fmaxf(t, 0.f);
        v[p] = t;
      }
      if (OUTBF) {
        vshort4 o;
#pragma unroll
        for (int p = 0; p < 4; p++) o[p] = f2bf(v[p]);
        if (SPLIT) {
          if (gc < 128) *(vshort4*)(Cb  + (size_t)gr * 128 + gc)       = o;
          else          *(vshort4*)(Cb2 + (size_t)gr * 128 + gc - 128) = o;
        } else {
          *(vshort4*)(Cb + (size_t)gr * Nc + gc) = o;
        }
      } else {
        *(vfloat4*)(Cf + (size_t)gr * Nc + gc) = v;
      }
    }
  }
  if (STATS) {
    for (int o2 = 32; o2; o2 >>= 1) {
      s  += __shfl_down(s,  o2, 64);
      s2 += __shfl_down(s2, o2, 64);
    }
    __shared__ float ps[8];
    if (lane == 0) { ps[wave] = s; ps[wave + 4] = s2; }
    __syncthreads();
    if (tid == 0) {
      atomicAdd(&statsOut[0], ps[0] + ps[1] + ps[2] + ps[3]);
      atomicAdd(&statsOut[1], ps[4] + ps[5] + ps[6] + ps[7]);
    }
  }
}

extern "C" void kernel_launch(void* const* d_in, const int* in_sizes, int n_in,
                              void* d_out, int out_size, void* d_ws, size_t ws_size,
                              hipStream_t stream) {
  const float* x    = (const float*)d_in[0];
  const void*  edge = d_in[1];
  const float* Wl1  = (const float*)d_in[2];
  const float* bl1  = (const float*)d_in[3];
  const float* Wr1  = (const float*)d_in[4];
  const float* ln1w = (const float*)d_in[5];
  const float* ln1b = (const float*)d_in[6];
  const float* W1   = (const float*)d_in[7];
  const float* b1   = (const float*)d_in[8];
  const float* W2   = (const float*)d_in[9];
  const float* b2   = (const float*)d_in[10];
  const float* Wl2  = (const float*)d_in[11];
  const float* bl2  = (const float*)d_in[12];
  const float* Wr2  = (const float*)d_in[13];
  const float* ln2w = (const float*)d_in[14];
  const float* ln2b = (const float*)d_in[15];
  const float* W3   = (const float*)d_in[16];
  const float* b3   = (const float*)d_in[17];
  const float* W4   = (const float*)d_in[18];
  const float* b4   = (const float*)d_in[19];
  float* out = (float*)d_out;

  char* wsp = (char*)d_ws;
  size_t o = 0;
  auto alloc = [&](size_t bytes) -> void* {
    void* p = wsp + o;
    o = (o + bytes + 255) & ~(size_t)255;
    return p;
  };
  // Footprint ~82 MB (< R2's proven-safe 94.6 MB).
  int*   flag   = (int*)alloc(4);
  int*   deg    = (int*)alloc((size_t)NN * 4);
  int*   iscan  = (int*)alloc((size_t)NN * 4);
  int*   bsum   = (int*)alloc((size_t)NBLK * 4);
  int*   offs   = (int*)alloc((size_t)(NN + 1) * 4);
  int*   cursor = (int*)alloc((size_t)NN * 4);
  int*   csr    = (int*)alloc((size_t)EE * 4);
  float* stats  = (float*)alloc(32);
  float* cbias  = (float*)alloc(256 * 4);
  short* wc1T   = (short*)alloc(256 * 256 * 2);
  short* w1T    = (short*)alloc(512 * 256 * 2);
  short* w2T    = (short*)alloc(256 * 512 * 2);
  short* wlr2T  = (short*)alloc(256 * 256 * 2);
  short* w3T    = (short*)alloc(256 * 128 * 2);
  short* w4T    = (short*)alloc(128 * 256 * 2);
  char*  bufB   = (char*)alloc((size_t)MPAD * 512);    // 25.6 MB
  char*  bufA   = (char*)alloc((size_t)MPAD * 1024);   // 51.2 MB

  const size_t Q = (size_t)MPAD * 256;   // 12.8 MB quarter of bufA
  // bufA timeline: xbf@0 -> h1@0(25.6) -> h_b@0(51.2) ->
  //   p2@0 | r2@Q | a2@2Q | h_d@3Q -> h_e@0 -> h_f@Q(25.6)
  short* xbf = (short*)bufA;
  short* h1  = (short*)bufA;
  short* h_b = (short*)bufA;
  short* p2  = (short*)bufA;
  short* r2  = (short*)(bufA + Q);
  short* a2  = (short*)(bufA + 2 * Q);
  short* h_d = (short*)(bufA + 3 * Q);
  short* h_e = (short*)bufA;
  short* h_f = (short*)(bufA + Q);
  // bufB timeline: hcat1 -> h_a -> h_c
  short* hcat1 = (short*)bufB;
  short* h_a   = (short*)bufB;
  short* h_c   = (short*)bufB;

  hipMemsetAsync(deg, 0, (size_t)NN * 4, stream);
  hipMemsetAsync(stats, 0, 32, stream);
  detect_kernel<<<1, 256, 0, stream>>>((const unsigned*)edge, flag);
  degree_kernel<<<(EE + 255) / 256, 256, 0, stream>>>(edge, flag, deg);
  scan_local<<<NBLK, 256, 0, stream>>>(deg, iscan, bsum);
  scan_apply<<<NBLK, 256, 0, stream>>>(iscan, bsum, offs, cursor);
  fill_kernel<<<(EE + 255) / 256, 256, 0, stream>>>(edge, flag, cursor, csr);

  xcast_kernel<<<(NN * 128 / 8 + 255) / 256, 256, 0, stream>>>(x, xbf);
  prep_all<<<1792, 256, 0, stream>>>(Wl1, Wr1, W1, W2, Wl2, Wr2, W3, W4,
                                     wc1T, w1T, w2T, wlr2T, w3T, w4T);
  prep_bias<<<1, 256, 0, stream>>>(bl2, cbias);

  // ---- layer 1 ----
  agg_mean<1><<<MPAD / 4, 256, 0, stream>>>(xbf, offs, csr, hcat1);
  gemm_bt<0, 1, 1, 1, 0><<<dim3(2, MPAD / 128), 256, 0, stream>>>(
      hcat1, wc1T, bl1, nullptr, h1, nullptr, stats, 256, 256, NN);
  ln_apply<<<(MPAD * 256 / 4 + 255) / 256, 256, 0, stream>>>(
      h1, stats, ln1w, ln1b, h_a, NN * 256, MPAD * 256, 256, 1.f / (NN * 256.f));
  gemm_bt<1, 1, 0, 0, 0><<<dim3(4, MPAD / 128), 256, 0, stream>>>(
      h_a, w1T, b1, nullptr, h_b, nullptr, nullptr, 512, 256, MPAD);
  gemm_bt<1, 1, 0, 0, 0><<<dim3(2, MPAD / 128), 256, 0, stream>>>(
      h_b, w2T, b2, nullptr, h_c, nullptr, nullptr, 256, 512, MPAD);

  // ---- layer 2: fused dual projection, then aggregate ----
  gemm_bt<0, 1, 0, 0, 1><<<dim3(2, MPAD / 128), 256, 0, stream>>>(
      h_c, wlr2T, cbias, nullptr, p2, r2, nullptr, 256, 256, MPAD);
  agg_mean<0><<<MPAD / 4, 256, 0, stream>>>(p2, offs, csr, a2);
  add_stats<<<(MPAD * 128 / 8 + 255) / 256, 256, 0, stream>>>(r2, a2, h_d, stats + 2);
  ln_apply<<<(MPAD * 128 / 4 + 255) / 256, 256, 0, stream>>>(
      h_d, stats + 2, ln2w, ln2b, h_e, NN * 128, MPAD * 128, 128, 1.f / (NN * 128.f));
  gemm_bt<1, 1, 0, 0, 0><<<dim3(2, MPAD / 128), 256, 0, stream>>>(
      h_e, w3T, b3, nullptr, h_f, nullptr, nullptr, 256, 128, MPAD);
  gemm_bt<0, 0, 1, 0, 0><<<dim3(1, MPAD / 128), 256, 0, stream>>>(
      h_f, w4T, b4, out, nullptr, nullptr, nullptr, 128, 256, NN);
}

// Round 8
// 463.401 us; speedup vs baseline: 1.1878x; 1.1878x over previous
//
#include <hip/hip_runtime.h>

#define NN   50000
#define EE   800000
#define MPAD 50048   // 391 * 128
#define NBLK ((NN + 255) / 256)   // 196

typedef __bf16 bf16x8 __attribute__((ext_vector_type(8)));
typedef float  vfloat4 __attribute__((ext_vector_type(4)));
typedef short  vshort4 __attribute__((ext_vector_type(4)));
typedef short  vshort8 __attribute__((ext_vector_type(8)));

__device__ __forceinline__ short f2bf(float f) {
  union { float f; unsigned u; } v; v.f = f;
  unsigned r = v.u + 0x7FFFu + ((v.u >> 16) & 1u);   // RNE
  return (short)(r >> 16);
}
__device__ __forceinline__ float bf2f(short h) {
  union { unsigned u; float f; } v; v.u = ((unsigned)(unsigned short)h) << 16;
  return v.f;
}

__device__ __forceinline__ void load_lds16(const short* g, short* l) {
  __builtin_amdgcn_global_load_lds(
      (__attribute__((address_space(1))) void*)(void*)g,
      (__attribute__((address_space(3))) void*)(void*)l, 16, 0, 0);
}

// ---------------- edge dtype detect (int64 vs int32) ----------------
__global__ __launch_bounds__(256) void detect_kernel(const unsigned* __restrict__ e,
                                                     int* __restrict__ flag) {
  unsigned v = 0;
  for (int i = threadIdx.x; i < 2048; i += 256) v |= e[2 * i + 1];
  for (int o = 32; o; o >>= 1) v |= (unsigned)__shfl_down((int)v, o, 64);
  __shared__ unsigned r[4];
  if ((threadIdx.x & 63) == 0) r[threadIdx.x >> 6] = v;
  __syncthreads();
  if (threadIdx.x == 0) flag[0] = ((r[0] | r[1] | r[2] | r[3]) == 0) ? 1 : 0;
}

// ---------------- CSR build ----------------
__global__ __launch_bounds__(256) void degree_kernel(const void* __restrict__ edges,
                                                     const int* __restrict__ flag,
                                                     int* __restrict__ deg) {
  int e = blockIdx.x * 256 + threadIdx.x;
  if (e >= EE) return;
  int d = flag[0] ? (int)((const long long*)edges)[EE + e] : ((const int*)edges)[EE + e];
  atomicAdd(&deg[d], 1);
}

__global__ __launch_bounds__(256) void scan_local(const int* __restrict__ deg,
                                                  int* __restrict__ iscan,
                                                  int* __restrict__ bsum) {
  __shared__ int tmp[256];
  int t = threadIdx.x;
  int i = blockIdx.x * 256 + t;
  int v = (i < NN) ? deg[i] : 0;
  tmp[t] = v;
  __syncthreads();
  int acc = v;
  for (int d = 1; d < 256; d <<= 1) {
    int u = (t >= d) ? tmp[t - d] : 0;
    __syncthreads();
    acc += u;
    tmp[t] = acc;
    __syncthreads();
  }
  if (i < NN) iscan[i] = acc - v;     // exclusive within block
  if (t == 255) bsum[blockIdx.x] = acc;
}

__global__ __launch_bounds__(256) void scan_apply(const int* __restrict__ iscan,
                                                  const int* __restrict__ bsum,
                                                  int* __restrict__ offs,
                                                  int* __restrict__ cursor) {
  __shared__ int sh[256];
  int t = threadIdx.x;
  int v = (t < NBLK) ? bsum[t] : 0;
  sh[t] = (t < (int)blockIdx.x) ? v : 0;
  __syncthreads();
  for (int d = 128; d; d >>= 1) { if (t < d) sh[t] += sh[t + d]; __syncthreads(); }
  int base = sh[0];
  __syncthreads();
  sh[t] = v;
  __syncthreads();
  for (int d = 128; d; d >>= 1) { if (t < d) sh[t] += sh[t + d]; __syncthreads(); }
  int total = sh[0];
  int i = blockIdx.x * 256 + t;
  if (i < NN) { int off = iscan[i] + base; offs[i] = off; cursor[i] = off; }
  if (blockIdx.x == gridDim.x - 1 && t == 0) offs[NN] = total;
}

__global__ __launch_bounds__(256) void fill_kernel(const void* __restrict__ edges,
                                                   const int* __restrict__ flag,
                                                   int* __restrict__ cursor,
                                                   int* __restrict__ csr) {
  int e = blockIdx.x * 256 + threadIdx.x;
  if (e >= EE) return;
  int sv, dv;
  if (flag[0]) {
    sv = (int)((const long long*)edges)[e];
    dv = (int)((const long long*)edges)[EE + e];
  } else {
    sv = ((const int*)edges)[e];
    dv = ((const int*)edges)[EE + e];
  }
  int p = atomicAdd(&cursor[dv], 1);
  __builtin_nontemporal_store(sv, &csr[p]);   // avoid write-allocate ping-pong
}

// ---------------- x -> bf16 cast (NN x 128) ----------------
__global__ __launch_bounds__(256) void xcast_kernel(const float* __restrict__ x,
                                                    short* __restrict__ xbf) {
  int i = blockIdx.x * 256 + threadIdx.x;   // one per 8 elems
  if (i >= NN * 128 / 8) return;
  vfloat4 v0 = *(const vfloat4*)(x + (size_t)i * 8);
  vfloat4 v1 = *(const vfloat4*)(x + (size_t)i * 8 + 4);
  vshort8 o;
  o[0] = f2bf(v0.x); o[1] = f2bf(v0.y); o[2] = f2bf(v0.z); o[3] = f2bf(v0.w);
  o[4] = f2bf(v1.x); o[5] = f2bf(v1.y); o[6] = f2bf(v1.z); o[7] = f2bf(v1.w);
  *(vshort8*)(xbf + (size_t)i * 8) = o;
}

// ---------------- all weight preps in one launch ----------------
__global__ __launch_bounds__(256) void prep_all(
    const float* __restrict__ Wl1, const float* __restrict__ Wr1,
    const float* __restrict__ W1,  const float* __restrict__ W2,
    const float* __restrict__ Wl2, const float* __restrict__ Wr2,
    const float* __restrict__ W3,  const float* __restrict__ W4,
    short* __restrict__ wc1T, short* __restrict__ w1T, short* __restrict__ w2T,
    short* __restrict__ wlr2T, short* __restrict__ w3T, short* __restrict__ w4T) {
  int b = blockIdx.x;
  if (b >= 1280 && b < 1536) {
    // wlr2T: col-split concat [Wl2 | Wr2], 256 cols x 256 k
    int idx = (b - 1280) * 256 + threadIdx.x;
    int n = idx >> 8, k = idx & 255;
    float v = (n < 128) ? Wl2[(size_t)k * 128 + n] : Wr2[(size_t)k * 128 + (n - 128)];
    wlr2T[idx] = f2bf(v);
    return;
  }
  const float *s0, *s1; short* dst; int K0, logK, Nc, base;
  if      (b <  256) { s0=Wl1; s1=Wr1; dst=wc1T; K0=128; logK=8; Nc=256; base=0;    }
  else if (b <  768) { s0=W1;  s1=W1;  dst=w1T;  K0=256; logK=8; Nc=512; base=256;  }
  else if (b < 1280) { s0=W2;  s1=W2;  dst=w2T;  K0=512; logK=9; Nc=256; base=768;  }
  else if (b < 1664) { s0=W3;  s1=W3;  dst=w3T;  K0=128; logK=7; Nc=256; base=1536; }
  else               { s0=W4;  s1=W4;  dst=w4T;  K0=256; logK=8; Nc=128; base=1664; }
  int idx = (b - base) * 256 + threadIdx.x;
  int n = idx >> logK, k = idx & ((1 << logK) - 1);
  float v = (k < K0) ? s0[(size_t)k * Nc + n] : s1[(size_t)(k - K0) * Nc + n];
  dst[idx] = f2bf(v);
}

// cbias[256] = [0 x128 | bl2]
__global__ __launch_bounds__(256) void prep_bias(const float* __restrict__ bl2,
                                                 float* __restrict__ cbias) {
  int t = threadIdx.x;
  cbias[t] = (t < 128) ? 0.f : bl2[t - 128];
}

// ---------------- partial-sum reduce (1 block): out[0]=sum s, out[1]=sum s2 --
__global__ __launch_bounds__(256) void reduce_stats(const float* __restrict__ part,
                                                    int n, float* __restrict__ out) {
  float s = 0.f, s2 = 0.f;
  for (int i = threadIdx.x; i < n; i += 256) { s += part[2 * i]; s2 += part[2 * i + 1]; }
  for (int o = 32; o; o >>= 1) {
    s  += __shfl_down(s,  o, 64);
    s2 += __shfl_down(s2, o, 64);
  }
  __shared__ float ps[8];
  int lane = threadIdx.x & 63, wv = threadIdx.x >> 6;
  if (lane == 0) { ps[wv] = s; ps[wv + 4] = s2; }
  __syncthreads();
  if (threadIdx.x == 0) {
    out[0] = ps[0] + ps[1] + ps[2] + ps[3];
    out[1] = ps[4] + ps[5] + ps[6] + ps[7];
  }
}

// ---------------- mean aggregation over 128-elem bf16 rows (256 B) ----------
// 1 wave/node; 4 lane-groups of 16. All __shfl with FULL wave active (R4
// lesson). CONCAT=1 also copies node's own row into dst second half.
template<int CONCAT>
__global__ __launch_bounds__(256) void agg_mean(const short* __restrict__ src,
                                                const int* __restrict__ offs,
                                                const int* __restrict__ csr,
                                                short* __restrict__ dst) {
  int node = blockIdx.x * 4 + (threadIdx.x >> 6);
  int lane = threadIdx.x & 63;
  if (node >= MPAD) return;
  short* row = dst + (size_t)node * (CONCAT ? 256 : 128);
  if (node >= NN) {
    if (CONCAT) *(vshort4*)(row + lane * 4) = (vshort4){0, 0, 0, 0};
    else if (lane < 32) *(vshort4*)(row + lane * 4) = (vshort4){0, 0, 0, 0};
    return;
  }
  int g = lane >> 4, sub = lane & 15;
  int e0 = offs[node], e1 = offs[node + 1];
  float a0[8] = {0, 0, 0, 0, 0, 0, 0, 0};
  float a1[8] = {0, 0, 0, 0, 0, 0, 0, 0};
  int e = e0;
  while (e < e1) {                         // wave-uniform
    int cnt = e1 - e; if (cnt > 64) cnt = 64;
    int myidx = (lane < cnt) ? csr[e + lane] : 0;
    for (int i = 0; i < cnt; i += 8) {     // wave-uniform bound
      int p0 = g + i;
      int p1 = g + i + 4;
      int s0 = __shfl(myidx, p0, 64);      // full wave active
      int s1 = __shfl(myidx, p1, 64);
      if (p0 < cnt) {
        vshort8 v0 = *(const vshort8*)(src + (size_t)s0 * 128 + sub * 8);
#pragma unroll
        for (int j = 0; j < 8; j++) a0[j] += bf2f(v0[j]);
      }
      if (p1 < cnt) {
        vshort8 v1 = *(const vshort8*)(src + (size_t)s1 * 128 + sub * 8);
#pragma unroll
        for (int j = 0; j < 8; j++) a1[j] += bf2f(v1[j]);
      }
    }
    e += cnt;
  }
#pragma unroll
  for (int j = 0; j < 8; j++) {
    a0[j] += a1[j];
    a0[j] += __shfl_down(a0[j], 32, 64);
    a0[j] += __shfl_down(a0[j], 16, 64);
  }
  float inv = (e1 > e0) ? 1.f / (float)(e1 - e0) : 0.f;
  if (g == 0) {
    vshort8 o;
#pragma unroll
    for (int j = 0; j < 8; j++) o[j] = f2bf(a0[j] * inv);
    *(vshort8*)(row + sub * 8) = o;
  } else if (CONCAT && g == 1) {
    *(vshort8*)(row + 128 + sub * 8) = *(const vshort8*)(src + (size_t)node * 128 + sub * 8);
  }
}

// ---------------- h_d = r2 + a2 (bf16), per-block stats partials ------------
__global__ __launch_bounds__(256) void add_stats(const short* __restrict__ r2,
                                                 const short* __restrict__ a2,
                                                 short* __restrict__ h_d,
                                                 float* __restrict__ partials) {
  int i = blockIdx.x * 256 + threadIdx.x;   // per 8 elems
  const int tot8 = MPAD * 128 / 8, real8 = NN * 128 / 8;
  float s = 0.f, s2 = 0.f;
  if (i < tot8) {
    if (i >= real8) {
      *(vshort8*)(h_d + (size_t)i * 8) = (vshort8){0,0,0,0,0,0,0,0};
    } else {
      vshort8 rv = *(const vshort8*)(r2 + (size_t)i * 8);
      vshort8 av = *(const vshort8*)(a2 + (size_t)i * 8);
      vshort8 o;
#pragma unroll
      for (int j = 0; j < 8; j++) {
        float v = bf2f(rv[j]) + bf2f(av[j]);
        s += v; s2 += v * v;
        o[j] = f2bf(v);
      }
      *(vshort8*)(h_d + (size_t)i * 8) = o;
    }
  }
  int lane = threadIdx.x & 63, wave = threadIdx.x >> 6;
  for (int o2 = 32; o2; o2 >>= 1) {
    s  += __shfl_down(s,  o2, 64);
    s2 += __shfl_down(s2, o2, 64);
  }
  __shared__ float ps[8];
  if (lane == 0) { ps[wave] = s; ps[wave + 4] = s2; }
  __syncthreads();
  if (threadIdx.x == 0) {
    // R7 post-mortem: atomicAdd to one address from 3128 blocks serialized
    // (~13ns each) -> 84us kernel. Plain per-block stores + reduce kernel.
    partials[2 * blockIdx.x]     = ps[0] + ps[1] + ps[2] + ps[3];
    partials[2 * blockIdx.x + 1] = ps[4] + ps[5] + ps[6] + ps[7];
  }
}

// ---------------- graph LayerNorm apply (bf16 in) ----------------
__global__ __launch_bounds__(256) void ln_apply(const short* __restrict__ h,
                                                const float* __restrict__ stats,
                                                const float* __restrict__ w,
                                                const float* __restrict__ b,
                                                short* __restrict__ out,
                                                int realElems, int totElems, int F,
                                                float invCount) {
  int base = (blockIdx.x * blockDim.x + threadIdx.x) * 4;
  if (base >= totElems) return;
  if (base >= realElems) { *(vshort4*)(out + base) = (vshort4){0,0,0,0}; return; }
  float mu  = stats[0] * invCount;
  float var = stats[1] * invCount - mu * mu;
  float rs  = rsqrtf(var + 1e-5f);
  int col = base % F;
  vshort4 hv = *(const vshort4*)(h + base);
  vshort4 o;
  o.x = f2bf(fmaxf((bf2f(hv.x) - mu) * rs * w[col]     + b[col],     0.f));
  o.y = f2bf(fmaxf((bf2f(hv.y) - mu) * rs * w[col + 1] + b[col + 1], 0.f));
  o.z = f2bf(fmaxf((bf2f(hv.z) - mu) * rs * w[col + 2] + b[col + 2], 0.f));
  o.w = f2bf(fmaxf((bf2f(hv.w) - mu) * rs * w[col + 3] + b[col + 3], 0.f));
  *(vshort4*)(out + base) = o;
}

// ---------------- GEMM: C = A(MxK) * BT(NcxK)^T + bias --------------------
// BK=64, XOR-swizzled LDS, swapped mfma operands (acc reg = 4 consecutive
// cols -> vectorized epilogue). SPLIT=1: Nc=256, cols<128 -> Cb, cols>=128 ->
// Cb2 (both stride 128). STATS=1: per-block (s,s2) partials (NO atomics).
template<int RELU, int OUTBF, int BOUND, int STATS, int SPLIT>
__global__ __launch_bounds__(256) void gemm_bt(const short* __restrict__ A,
                                               const short* __restrict__ BT,
                                               const float* __restrict__ bias,
                                               float* __restrict__ Cf,
                                               short* __restrict__ Cb,
                                               short* __restrict__ Cb2,
                                               float* __restrict__ partials,
                                               int Nc, int K, int Mreal) {
  __shared__ short lsA[128 * 64];   // 16 KB, XOR-swizzled
  __shared__ short lsB[128 * 64];
  const int tid  = threadIdx.x;
  const int lane = tid & 63;
  const int wave = tid >> 6;
  const int wr   = (wave >> 1) << 6;
  const int wc   = (wave & 1) << 6;
  const int row0 = blockIdx.y << 7;
  const int col0 = blockIdx.x << 7;
  const int r16  = lane & 15;
  const int quad = lane >> 4;
  const int srow   = lane >> 3;
  const int schunk = lane & 7;
  const int sxoff  = ((schunk ^ srow) << 3);

  vfloat4 acc[4][4];
#pragma unroll
  for (int i = 0; i < 4; i++)
#pragma unroll
    for (int j = 0; j < 4; j++) acc[i][j] = (vfloat4){0.f, 0.f, 0.f, 0.f};

  for (int k0 = 0; k0 < K; k0 += 64) {
    __syncthreads();
#pragma unroll
    for (int t = 0; t < 4; t++) {
      int seg  = (wave << 2) + t;
      int trow = (seg << 3) + srow;
      load_lds16(A  + (size_t)(row0 + trow) * K + k0 + sxoff, lsA + (seg << 9) + lane * 8);
      load_lds16(BT + (size_t)(col0 + trow) * K + k0 + sxoff, lsB + (seg << 9) + lane * 8);
    }
    __syncthreads();
#pragma unroll
    for (int kk = 0; kk < 64; kk += 32) {
      int kf8 = (kk >> 3) + quad;
      bf16x8 af[4], bfr[4];
#pragma unroll
      for (int i = 0; i < 4; i++) {
        int r = wr + (i << 4) + r16;
        af[i] = *(const bf16x8*)(lsA + (r << 6) + ((kf8 ^ (r & 7)) << 3));
      }
#pragma unroll
      for (int j = 0; j < 4; j++) {
        int r = wc + (j << 4) + r16;
        bfr[j] = *(const bf16x8*)(lsB + (r << 6) + ((kf8 ^ (r & 7)) << 3));
      }
#pragma unroll
      for (int i = 0; i < 4; i++)
#pragma unroll
        for (int j = 0; j < 4; j++)
          acc[i][j] = __builtin_amdgcn_mfma_f32_16x16x32_bf16(bfr[j], af[i], acc[i][j], 0, 0, 0);
    }
  }

  float s = 0.f, s2 = 0.f;
#pragma unroll
  for (int i = 0; i < 4; i++) {
    int gr = row0 + wr + (i << 4) + r16;
    if (BOUND && gr >= Mreal) continue;
#pragma unroll
    for (int j = 0; j < 4; j++) {
      int gc = col0 + wc + (j << 4) + (quad << 2);
      vfloat4 bv = *(const vfloat4*)(bias + gc);
      vfloat4 v;
#pragma unroll
      for (int p = 0; p < 4; p++) {
        float t = acc[i][j][p] + bv[p];
        if (STATS) { s += t; s2 += t * t; }
        if (RELU) t = fmaxf(t, 0.f);
        v[p] = t;
      }
      if (OUTBF) {
        vshort4 o;
#pragma unroll
        for (int p = 0; p < 4; p++) o[p] = f2bf(v[p]);
        if (SPLIT) {
          if (gc < 128) *(vshort4*)(Cb  + (size_t)gr * 128 + gc)       = o;
          else          *(vshort4*)(Cb2 + (size_t)gr * 128 + gc - 128) = o;
        } else {
          *(vshort4*)(Cb + (size_t)gr * Nc + gc) = o;
        }
      } else {
        *(vfloat4*)(Cf + (size_t)gr * Nc + gc) = v;
      }
    }
  }
  if (STATS) {
    for (int o2 = 32; o2; o2 >>= 1) {
      s  += __shfl_down(s,  o2, 64);
      s2 += __shfl_down(s2, o2, 64);
    }
    __shared__ float ps[8];
    if (lane == 0) { ps[wave] = s; ps[wave + 4] = s2; }
    __syncthreads();
    if (tid == 0) {
      int bid = blockIdx.y * gridDim.x + blockIdx.x;
      partials[2 * bid]     = ps[0] + ps[1] + ps[2] + ps[3];
      partials[2 * bid + 1] = ps[4] + ps[5] + ps[6] + ps[7];
    }
  }
}

extern "C" void kernel_launch(void* const* d_in, const int* in_sizes, int n_in,
                              void* d_out, int out_size, void* d_ws, size_t ws_size,
                              hipStream_t stream) {
  const float* x    = (const float*)d_in[0];
  const void*  edge = d_in[1];
  const float* Wl1  = (const float*)d_in[2];
  const float* bl1  = (const float*)d_in[3];
  const float* Wr1  = (const float*)d_in[4];
  const float* ln1w = (const float*)d_in[5];
  const float* ln1b = (const float*)d_in[6];
  const float* W1   = (const float*)d_in[7];
  const float* b1   = (const float*)d_in[8];
  const float* W2   = (const float*)d_in[9];
  const float* b2   = (const float*)d_in[10];
  const float* Wl2  = (const float*)d_in[11];
  const float* bl2  = (const float*)d_in[12];
  const float* Wr2  = (const float*)d_in[13];
  const float* ln2w = (const float*)d_in[14];
  const float* ln2b = (const float*)d_in[15];
  const float* W3   = (const float*)d_in[16];
  const float* b3   = (const float*)d_in[17];
  const float* W4   = (const float*)d_in[18];
  const float* b4   = (const float*)d_in[19];
  float* out = (float*)d_out;

  char* wsp = (char*)d_ws;
  size_t o = 0;
  auto alloc = [&](size_t bytes) -> void* {
    void* p = wsp + o;
    o = (o + bytes + 255) & ~(size_t)255;
    return p;
  };
  // Footprint ~82 MB (< R2's proven-safe 94.6 MB).
  int*   flag   = (int*)alloc(4);
  int*   deg    = (int*)alloc((size_t)NN * 4);
  int*   iscan  = (int*)alloc((size_t)NN * 4);
  int*   bsum   = (int*)alloc((size_t)NBLK * 4);
  int*   offs   = (int*)alloc((size_t)(NN + 1) * 4);
  int*   cursor = (int*)alloc((size_t)NN * 4);
  int*   csr    = (int*)alloc((size_t)EE * 4);
  float* stats  = (float*)alloc(32);
  float* cbias  = (float*)alloc(256 * 4);
  float* pb1    = (float*)alloc(782 * 2 * 4);    // gemm1 stats partials
  float* pb2    = (float*)alloc(3128 * 2 * 4);   // add_stats partials
  short* wc1T   = (short*)alloc(256 * 256 * 2);
  short* w1T    = (short*)alloc(512 * 256 * 2);
  short* w2T    = (short*)alloc(256 * 512 * 2);
  short* wlr2T  = (short*)alloc(256 * 256 * 2);
  short* w3T    = (short*)alloc(256 * 128 * 2);
  short* w4T    = (short*)alloc(128 * 256 * 2);
  char*  bufB   = (char*)alloc((size_t)MPAD * 512);    // 25.6 MB
  char*  bufA   = (char*)alloc((size_t)MPAD * 1024);   // 51.2 MB

  const size_t Q = (size_t)MPAD * 256;   // 12.8 MB quarter of bufA
  // bufA timeline: xbf@0 -> h1@0(25.6) -> h_b@0(51.2) ->
  //   p2@0 | r2@Q | a2@2Q | h_d@3Q -> h_e@0 -> h_f@Q(25.6)
  short* xbf = (short*)bufA;
  short* h1  = (short*)bufA;
  short* h_b = (short*)bufA;
  short* p2  = (short*)bufA;
  short* r2  = (short*)(bufA + Q);
  short* a2  = (short*)(bufA + 2 * Q);
  short* h_d = (short*)(bufA + 3 * Q);
  short* h_e = (short*)bufA;
  short* h_f = (short*)(bufA + Q);
  // bufB timeline: hcat1 -> h_a -> h_c
  short* hcat1 = (short*)bufB;
  short* h_a   = (short*)bufB;
  short* h_c   = (short*)bufB;

  hipMemsetAsync(deg, 0, (size_t)NN * 4, stream);
  detect_kernel<<<1, 256, 0, stream>>>((const unsigned*)edge, flag);
  degree_kernel<<<(EE + 255) / 256, 256, 0, stream>>>(edge, flag, deg);
  scan_local<<<NBLK, 256, 0, stream>>>(deg, iscan, bsum);
  scan_apply<<<NBLK, 256, 0, stream>>>(iscan, bsum, offs, cursor);
  fill_kernel<<<(EE + 255) / 256, 256, 0, stream>>>(edge, flag, cursor, csr);

  xcast_kernel<<<(NN * 128 / 8 + 255) / 256, 256, 0, stream>>>(x, xbf);
  prep_all<<<1792, 256, 0, stream>>>(Wl1, Wr1, W1, W2, Wl2, Wr2, W3, W4,
                                     wc1T, w1T, w2T, wlr2T, w3T, w4T);
  prep_bias<<<1, 256, 0, stream>>>(bl2, cbias);

  // ---- layer 1 ----
  agg_mean<1><<<MPAD / 4, 256, 0, stream>>>(xbf, offs, csr, hcat1);
  gemm_bt<0, 1, 1, 1, 0><<<dim3(2, MPAD / 128), 256, 0, stream>>>(
      hcat1, wc1T, bl1, nullptr, h1, nullptr, pb1, 256, 256, NN);
  reduce_stats<<<1, 256, 0, stream>>>(pb1, 782, stats);
  ln_apply<<<(MPAD * 256 / 4 + 255) / 256, 256, 0, stream>>>(
      h1, stats, ln1w, ln1b, h_a, NN * 256, MPAD * 256, 256, 1.f / (NN * 256.f));
  gemm_bt<1, 1, 0, 0, 0><<<dim3(4, MPAD / 128), 256, 0, stream>>>(
      h_a, w1T, b1, nullptr, h_b, nullptr, nullptr, 512, 256, MPAD);
  gemm_bt<1, 1, 0, 0, 0><<<dim3(2, MPAD / 128), 256, 0, stream>>>(
      h_b, w2T, b2, nullptr, h_c, nullptr, nullptr, 256, 512, MPAD);

  // ---- layer 2: fused dual projection, then aggregate ----
  gemm_bt<0, 1, 0, 0, 1><<<dim3(2, MPAD / 128), 256, 0, stream>>>(
      h_c, wlr2T, cbias, nullptr, p2, r2, nullptr, 256, 256, MPAD);
  agg_mean<0><<<MPAD / 4, 256, 0, stream>>>(p2, offs, csr, a2);
  add_stats<<<MPAD * 128 / 8 / 256, 256, 0, stream>>>(r2, a2, h_d, pb2);
  reduce_stats<<<1, 256, 0, stream>>>(pb2, 3128, stats + 2);
  ln_apply<<<(MPAD * 128 / 4 + 255) / 256, 256, 0, stream>>>(
      h_d, stats + 2, ln2w, ln2b, h_e, NN * 128, MPAD * 128, 128, 1.f / (NN * 128.f));
  gemm_bt<1, 1, 0, 0, 0><<<dim3(2, MPAD / 128), 256, 0, stream>>>(
      h_e, w3T, b3, nullptr, h_f, nullptr, nullptr, 256, 128, MPAD);
  gemm_bt<0, 0, 1, 0, 0><<<dim3(1, MPAD / 128), 256, 0, stream>>>(
      h_f, w4T, b4, out, nullptr, nullptr, nullptr, 128, 256, NN);
}

// Round 9
// 403.024 us; speedup vs baseline: 1.3657x; 1.1498x over previous
//
#include <hip/hip_runtime.h>

#define NN   50000
#define EE   800000
#define MPAD 50048   // 391 * 128
#define NBUCK 196    // dst>>8 buckets (256 nodes each)

typedef __bf16 bf16x8 __attribute__((ext_vector_type(8)));
typedef float  vfloat4 __attribute__((ext_vector_type(4)));
typedef short  vshort4 __attribute__((ext_vector_type(4)));
typedef short  vshort8 __attribute__((ext_vector_type(8)));

__device__ __forceinline__ short f2bf(float f) {
  union { float f; unsigned u; } v; v.f = f;
  unsigned r = v.u + 0x7FFFu + ((v.u >> 16) & 1u);   // RNE
  return (short)(r >> 16);
}
__device__ __forceinline__ float bf2f(short h) {
  union { unsigned u; float f; } v; v.u = ((unsigned)(unsigned short)h) << 16;
  return v.f;
}

__device__ __forceinline__ void load_lds16(const short* g, short* l) {
  __builtin_amdgcn_global_load_lds(
      (__attribute__((address_space(1))) void*)(void*)g,
      (__attribute__((address_space(3))) void*)(void*)l, 16, 0, 0);
}

// ---------------- edge dtype detect (int64 vs int32) ----------------
__global__ __launch_bounds__(256) void detect_kernel(const unsigned* __restrict__ e,
                                                     int* __restrict__ flag) {
  unsigned v = 0;
  for (int i = threadIdx.x; i < 2048; i += 256) v |= e[2 * i + 1];
  for (int o = 32; o; o >>= 1) v |= (unsigned)__shfl_down((int)v, o, 64);
  __shared__ unsigned r[4];
  if ((threadIdx.x & 63) == 0) r[threadIdx.x >> 6] = v;
  __syncthreads();
  if (threadIdx.x == 0) flag[0] = ((r[0] | r[1] | r[2] | r[3]) == 0) ? 1 : 0;
}

// ---------------- CSR build: 2-level bucket sort ----------------
// R8 post-mortem: random 4B scatter (fill_kernel) had 19x write amplification
// (61MB HBM writes for 3.2MB csr). Bucket by dst>>8 first: scatter becomes
// bucket-local bursts; per-bucket CSR build is L2-resident.

// A1: per-block LDS histogram, 1 global atomic per bucket per block.
__global__ __launch_bounds__(256) void bin_count(const void* __restrict__ edges,
                                                 const int* __restrict__ flag,
                                                 int* __restrict__ bcnt) {
  __shared__ int h[NBUCK];
  int t = threadIdx.x;
  for (int i = t; i < NBUCK; i += 256) h[i] = 0;
  __syncthreads();
  const int per = (EE + NBUCK - 1) / NBUCK;
  int lo = blockIdx.x * per, hi = lo + per;
  if (hi > EE) hi = EE;
  int fl = flag[0];
  for (int e = lo + t; e < hi; e += 256) {
    int dv = fl ? (int)((const long long*)edges)[EE + e] : ((const int*)edges)[EE + e];
    atomicAdd(&h[dv >> 8], 1);
  }
  __syncthreads();
  for (int i = t; i < NBUCK; i += 256)
    if (h[i]) atomicAdd(&bcnt[i], h[i]);
}

// exclusive scan of 196 bucket counts -> bstart[197], bcur
__global__ __launch_bounds__(256) void bin_scan(const int* __restrict__ bcnt,
                                                int* __restrict__ bstart,
                                                int* __restrict__ bcur) {
  __shared__ int tmp[256];
  int t = threadIdx.x;
  int v = (t < NBUCK) ? bcnt[t] : 0;
  tmp[t] = v;
  __syncthreads();
  int acc = v;
  for (int d = 1; d < 256; d <<= 1) {
    int u = (t >= d) ? tmp[t - d] : 0;
    __syncthreads();
    acc += u;
    tmp[t] = acc;
    __syncthreads();
  }
  int excl = acc - v;
  if (t < NBUCK) { bstart[t] = excl; bcur[t] = excl; }
  if (t == NBUCK - 1) bstart[NBUCK] = excl + v;   // == EE
}

// A2: per-block count -> one chunk reservation per bucket -> burst writes.
__global__ __launch_bounds__(256) void bin_scatter(const void* __restrict__ edges,
                                                   const int* __restrict__ flag,
                                                   int* __restrict__ bcur,
                                                   long long* __restrict__ staging) {
  __shared__ int h[NBUCK];
  __shared__ int base[NBUCK];
  int t = threadIdx.x;
  for (int i = t; i < NBUCK; i += 256) h[i] = 0;
  __syncthreads();
  const int per = (EE + NBUCK - 1) / NBUCK;
  int lo = blockIdx.x * per, hi = lo + per;
  if (hi > EE) hi = EE;
  int fl = flag[0];
  for (int e = lo + t; e < hi; e += 256) {
    int dv = fl ? (int)((const long long*)edges)[EE + e] : ((const int*)edges)[EE + e];
    atomicAdd(&h[dv >> 8], 1);
  }
  __syncthreads();
  for (int i = t; i < NBUCK; i += 256) {
    int c = h[i];
    base[i] = c ? atomicAdd(&bcur[i], c) : 0;
    h[i] = 0;                                   // reuse as rank cursor
  }
  __syncthreads();
  for (int e = lo + t; e < hi; e += 256) {
    int sv, dv;
    if (fl) { sv = (int)((const long long*)edges)[e]; dv = (int)((const long long*)edges)[EE + e]; }
    else    { sv = ((const int*)edges)[e];            dv = ((const int*)edges)[EE + e]; }
    int b = dv >> 8;
    int r = atomicAdd(&h[b], 1);
    staging[base[b] + r] = ((long long)sv << 32) | (unsigned)dv;
  }
}

// B: one block per bucket: local histogram + scan -> offs, LDS-cursor scatter
// into the bucket's contiguous (L2-resident) csr window.
__global__ __launch_bounds__(256) void bucket_csr(const int* __restrict__ bstart,
                                                  const long long* __restrict__ staging,
                                                  int* __restrict__ offs,
                                                  int* __restrict__ csr) {
  int b = blockIdx.x, t = threadIdx.x;
  int n0 = b << 8;
  int s0 = bstart[b], s1 = bstart[b + 1];
  __shared__ int cnt[256], tmp[256], cur[256];
  cnt[t] = 0;
  __syncthreads();
  for (int i = s0 + t; i < s1; i += 256)
    atomicAdd(&cnt[((int)(staging[i] & 0xffffffffLL)) - n0], 1);
  __syncthreads();
  int v = cnt[t];
  tmp[t] = v;
  __syncthreads();
  int acc = v;
  for (int d = 1; d < 256; d <<= 1) {
    int u = (t >= d) ? tmp[t - d] : 0;
    __syncthreads();
    acc += u;
    tmp[t] = acc;
    __syncthreads();
  }
  int excl = acc - v;
  int node = n0 + t;
  if (node < NN) offs[node] = s0 + excl;
  cur[t] = s0 + excl;
  __syncthreads();
  for (int i = s0 + t; i < s1; i += 256) {
    long long pk = staging[i];
    int dv = (int)(pk & 0xffffffffLL);
    int sv = (int)(pk >> 32);
    int p = atomicAdd(&cur[dv - n0], 1);
    csr[p] = sv;
  }
  if (b == 0 && t == 0) offs[NN] = EE;
}

// ---------------- x -> bf16 cast (NN x 128) ----------------
__global__ __launch_bounds__(256) void xcast_kernel(const float* __restrict__ x,
                                                    short* __restrict__ xbf) {
  int i = blockIdx.x * 256 + threadIdx.x;   // one per 8 elems
  if (i >= NN * 128 / 8) return;
  vfloat4 v0 = *(const vfloat4*)(x + (size_t)i * 8);
  vfloat4 v1 = *(const vfloat4*)(x + (size_t)i * 8 + 4);
  vshort8 o;
  o[0] = f2bf(v0.x); o[1] = f2bf(v0.y); o[2] = f2bf(v0.z); o[3] = f2bf(v0.w);
  o[4] = f2bf(v1.x); o[5] = f2bf(v1.y); o[6] = f2bf(v1.z); o[7] = f2bf(v1.w);
  *(vshort8*)(xbf + (size_t)i * 8) = o;
}

// ---------------- all weight preps in one launch ----------------
__global__ __launch_bounds__(256) void prep_all(
    const float* __restrict__ Wl1, const float* __restrict__ Wr1,
    const float* __restrict__ W1,  const float* __restrict__ W2,
    const float* __restrict__ Wl2, const float* __restrict__ Wr2,
    const float* __restrict__ W3,  const float* __restrict__ W4,
    short* __restrict__ wc1T, short* __restrict__ w1T, short* __restrict__ w2T,
    short* __restrict__ wlr2T, short* __restrict__ w3T, short* __restrict__ w4T) {
  int b = blockIdx.x;
  if (b >= 1280 && b < 1536) {
    int idx = (b - 1280) * 256 + threadIdx.x;
    int n = idx >> 8, k = idx & 255;
    float v = (n < 128) ? Wl2[(size_t)k * 128 + n] : Wr2[(size_t)k * 128 + (n - 128)];
    wlr2T[idx] = f2bf(v);
    return;
  }
  const float *s0, *s1; short* dst; int K0, logK, Nc, base;
  if      (b <  256) { s0=Wl1; s1=Wr1; dst=wc1T; K0=128; logK=8; Nc=256; base=0;    }
  else if (b <  768) { s0=W1;  s1=W1;  dst=w1T;  K0=256; logK=8; Nc=512; base=256;  }
  else if (b < 1280) { s0=W2;  s1=W2;  dst=w2T;  K0=512; logK=9; Nc=256; base=768;  }
  else if (b < 1664) { s0=W3;  s1=W3;  dst=w3T;  K0=128; logK=7; Nc=256; base=1536; }
  else               { s0=W4;  s1=W4;  dst=w4T;  K0=256; logK=8; Nc=128; base=1664; }
  int idx = (b - base) * 256 + threadIdx.x;
  int n = idx >> logK, k = idx & ((1 << logK) - 1);
  float v = (k < K0) ? s0[(size_t)k * Nc + n] : s1[(size_t)(k - K0) * Nc + n];
  dst[idx] = f2bf(v);
}

// cbias[256] = [0 x128 | bl2]
__global__ __launch_bounds__(256) void prep_bias(const float* __restrict__ bl2,
                                                 float* __restrict__ cbias) {
  int t = threadIdx.x;
  cbias[t] = (t < 128) ? 0.f : bl2[t - 128];
}

// ---------------- partial-sum reduce (1 block) ----------------
__global__ __launch_bounds__(256) void reduce_stats(const float* __restrict__ part,
                                                    int n, float* __restrict__ out) {
  float s = 0.f, s2 = 0.f;
  for (int i = threadIdx.x; i < n; i += 256) { s += part[2 * i]; s2 += part[2 * i + 1]; }
  for (int o = 32; o; o >>= 1) {
    s  += __shfl_down(s,  o, 64);
    s2 += __shfl_down(s2, o, 64);
  }
  __shared__ float ps[8];
  int lane = threadIdx.x & 63, wv = threadIdx.x >> 6;
  if (lane == 0) { ps[wv] = s; ps[wv + 4] = s2; }
  __syncthreads();
  if (threadIdx.x == 0) {
    out[0] = ps[0] + ps[1] + ps[2] + ps[3];
    out[1] = ps[4] + ps[5] + ps[6] + ps[7];
  }
}

// ---------------- mean aggregation over 128-elem bf16 rows (256 B) ----------
// 1 wave/node; 4 lane-groups of 16. All __shfl with FULL wave active (R4
// lesson). CONCAT=1 also copies node's own row into dst second half.
template<int CONCAT>
__global__ __launch_bounds__(256) void agg_mean(const short* __restrict__ src,
                                                const int* __restrict__ offs,
                                                const int* __restrict__ csr,
                                                short* __restrict__ dst) {
  int node = blockIdx.x * 4 + (threadIdx.x >> 6);
  int lane = threadIdx.x & 63;
  if (node >= MPAD) return;
  short* row = dst + (size_t)node * (CONCAT ? 256 : 128);
  if (node >= NN) {
    if (CONCAT) *(vshort4*)(row + lane * 4) = (vshort4){0, 0, 0, 0};
    else if (lane < 32) *(vshort4*)(row + lane * 4) = (vshort4){0, 0, 0, 0};
    return;
  }
  int g = lane >> 4, sub = lane & 15;
  int e0 = offs[node], e1 = offs[node + 1];
  float a0[8] = {0, 0, 0, 0, 0, 0, 0, 0};
  float a1[8] = {0, 0, 0, 0, 0, 0, 0, 0};
  int e = e0;
  while (e < e1) {                         // wave-uniform
    int cnt = e1 - e; if (cnt > 64) cnt = 64;
    int myidx = (lane < cnt) ? csr[e + lane] : 0;
    for (int i = 0; i < cnt; i += 8) {     // wave-uniform bound
      int p0 = g + i;
      int p1 = g + i + 4;
      int s0 = __shfl(myidx, p0, 64);      // full wave active
      int s1 = __shfl(myidx, p1, 64);
      if (p0 < cnt) {
        vshort8 v0 = *(const vshort8*)(src + (size_t)s0 * 128 + sub * 8);
#pragma unroll
        for (int j = 0; j < 8; j++) a0[j] += bf2f(v0[j]);
      }
      if (p1 < cnt) {
        vshort8 v1 = *(const vshort8*)(src + (size_t)s1 * 128 + sub * 8);
#pragma unroll
        for (int j = 0; j < 8; j++) a1[j] += bf2f(v1[j]);
      }
    }
    e += cnt;
  }
#pragma unroll
  for (int j = 0; j < 8; j++) {
    a0[j] += a1[j];
    a0[j] += __shfl_down(a0[j], 32, 64);
    a0[j] += __shfl_down(a0[j], 16, 64);
  }
  float inv = (e1 > e0) ? 1.f / (float)(e1 - e0) : 0.f;
  if (g == 0) {
    vshort8 o;
#pragma unroll
    for (int j = 0; j < 8; j++) o[j] = f2bf(a0[j] * inv);
    *(vshort8*)(row + sub * 8) = o;
  } else if (CONCAT && g == 1) {
    *(vshort8*)(row + 128 + sub * 8) = *(const vshort8*)(src + (size_t)node * 128 + sub * 8);
  }
}

// ---------------- h_d = r2 + a2 (bf16), per-block stats partials ------------
__global__ __launch_bounds__(256) void add_stats(const short* __restrict__ r2,
                                                 const short* __restrict__ a2,
                                                 short* __restrict__ h_d,
                                                 float* __restrict__ partials) {
  int i = blockIdx.x * 256 + threadIdx.x;   // per 8 elems
  const int tot8 = MPAD * 128 / 8, real8 = NN * 128 / 8;
  float s = 0.f, s2 = 0.f;
  if (i < tot8) {
    if (i >= real8) {
      *(vshort8*)(h_d + (size_t)i * 8) = (vshort8){0,0,0,0,0,0,0,0};
    } else {
      vshort8 rv = *(const vshort8*)(r2 + (size_t)i * 8);
      vshort8 av = *(const vshort8*)(a2 + (size_t)i * 8);
      vshort8 o;
#pragma unroll
      for (int j = 0; j < 8; j++) {
        float v = bf2f(rv[j]) + bf2f(av[j]);
        s += v; s2 += v * v;
        o[j] = f2bf(v);
      }
      *(vshort8*)(h_d + (size_t)i * 8) = o;
    }
  }
  int lane = threadIdx.x & 63, wave = threadIdx.x >> 6;
  for (int o2 = 32; o2; o2 >>= 1) {
    s  += __shfl_down(s,  o2, 64);
    s2 += __shfl_down(s2, o2, 64);
  }
  __shared__ float ps[8];
  if (lane == 0) { ps[wave] = s; ps[wave + 4] = s2; }
  __syncthreads();
  if (threadIdx.x == 0) {
    // per-block partials, no atomics (R7 lesson)
    partials[2 * blockIdx.x]     = ps[0] + ps[1] + ps[2] + ps[3];
    partials[2 * blockIdx.x + 1] = ps[4] + ps[5] + ps[6] + ps[7];
  }
}

// ---------------- graph LayerNorm apply (bf16 in) ----------------
__global__ __launch_bounds__(256) void ln_apply(const short* __restrict__ h,
                                                const float* __restrict__ stats,
                                                const float* __restrict__ w,
                                                const float* __restrict__ b,
                                                short* __restrict__ out,
                                                int realElems, int totElems, int F,
                                                float invCount) {
  int base = (blockIdx.x * blockDim.x + threadIdx.x) * 4;
  if (base >= totElems) return;
  if (base >= realElems) { *(vshort4*)(out + base) = (vshort4){0,0,0,0}; return; }
  float mu  = stats[0] * invCount;
  float var = stats[1] * invCount - mu * mu;
  float rs  = rsqrtf(var + 1e-5f);
  int col = base % F;
  vshort4 hv = *(const vshort4*)(h + base);
  vshort4 o;
  o.x = f2bf(fmaxf((bf2f(hv.x) - mu) * rs * w[col]     + b[col],     0.f));
  o.y = f2bf(fmaxf((bf2f(hv.y) - mu) * rs * w[col + 1] + b[col + 1], 0.f));
  o.z = f2bf(fmaxf((bf2f(hv.z) - mu) * rs * w[col + 2] + b[col + 2], 0.f));
  o.w = f2bf(fmaxf((bf2f(hv.w) - mu) * rs * w[col + 3] + b[col + 3], 0.f));
  *(vshort4*)(out + base) = o;
}

// ---------------- GEMM: C = A(MxK) * BT(NcxK)^T + bias --------------------
// BK=64, XOR-swizzled LDS, swapped mfma operands (acc reg = 4 consecutive
// cols -> vectorized epilogue). SPLIT=1: Nc=256, cols<128 -> Cb, cols>=128 ->
// Cb2 (both stride 128). STATS=1: per-block (s,s2) partials (NO atomics).
template<int RELU, int OUTBF, int BOUND, int STATS, int SPLIT>
__global__ __launch_bounds__(256) void gemm_bt(const short* __restrict__ A,
                                               const short* __restrict__ BT,
                                               const float* __restrict__ bias,
                                               float* __restrict__ Cf,
                                               short* __restrict__ Cb,
                                               short* __restrict__ Cb2,
                                               float* __restrict__ partials,
                                               int Nc, int K, int Mreal) {
  __shared__ short lsA[128 * 64];   // 16 KB, XOR-swizzled
  __shared__ short lsB[128 * 64];
  const int tid  = threadIdx.x;
  const int lane = tid & 63;
  const int wave = tid >> 6;
  const int wr   = (wave >> 1) << 6;
  const int wc   = (wave & 1) << 6;
  const int row0 = blockIdx.y << 7;
  const int col0 = blockIdx.x << 7;
  const int r16  = lane & 15;
  const int quad = lane >> 4;
  const int srow   = lane >> 3;
  const int schunk = lane & 7;
  const int sxoff  = ((schunk ^ srow) << 3);

  vfloat4 acc[4][4];
#pragma unroll
  for (int i = 0; i < 4; i++)
#pragma unroll
    for (int j = 0; j < 4; j++) acc[i][j] = (vfloat4){0.f, 0.f, 0.f, 0.f};

  for (int k0 = 0; k0 < K; k0 += 64) {
    __syncthreads();
#pragma unroll
    for (int t = 0; t < 4; t++) {
      int seg  = (wave << 2) + t;
      int trow = (seg << 3) + srow;
      load_lds16(A  + (size_t)(row0 + trow) * K + k0 + sxoff, lsA + (seg << 9) + lane * 8);
      load_lds16(BT + (size_t)(col0 + trow) * K + k0 + sxoff, lsB + (seg << 9) + lane * 8);
    }
    __syncthreads();
#pragma unroll
    for (int kk = 0; kk < 64; kk += 32) {
      int kf8 = (kk >> 3) + quad;
      bf16x8 af[4], bfr[4];
#pragma unroll
      for (int i = 0; i < 4; i++) {
        int r = wr + (i << 4) + r16;
        af[i] = *(const bf16x8*)(lsA + (r << 6) + ((kf8 ^ (r & 7)) << 3));
      }
#pragma unroll
      for (int j = 0; j < 4; j++) {
        int r = wc + (j << 4) + r16;
        bfr[j] = *(const bf16x8*)(lsB + (r << 6) + ((kf8 ^ (r & 7)) << 3));
      }
#pragma unroll
      for (int i = 0; i < 4; i++)
#pragma unroll
        for (int j = 0; j < 4; j++)
          acc[i][j] = __builtin_amdgcn_mfma_f32_16x16x32_bf16(bfr[j], af[i], acc[i][j], 0, 0, 0);
    }
  }

  float s = 0.f, s2 = 0.f;
#pragma unroll
  for (int i = 0; i < 4; i++) {
    int gr = row0 + wr + (i << 4) + r16;
    if (BOUND && gr >= Mreal) continue;
#pragma unroll
    for (int j = 0; j < 4; j++) {
      int gc = col0 + wc + (j << 4) + (quad << 2);
      vfloat4 bv = *(const vfloat4*)(bias + gc);
      vfloat4 v;
#pragma unroll
      for (int p = 0; p < 4; p++) {
        float t = acc[i][j][p] + bv[p];
        if (STATS) { s += t; s2 += t * t; }
        if (RELU) t = fmaxf(t, 0.f);
        v[p] = t;
      }
      if (OUTBF) {
        vshort4 o;
#pragma unroll
        for (int p = 0; p < 4; p++) o[p] = f2bf(v[p]);
        if (SPLIT) {
          if (gc < 128) *(vshort4*)(Cb  + (size_t)gr * 128 + gc)       = o;
          else          *(vshort4*)(Cb2 + (size_t)gr * 128 + gc - 128) = o;
        } else {
          *(vshort4*)(Cb + (size_t)gr * Nc + gc) = o;
        }
      } else {
        *(vfloat4*)(Cf + (size_t)gr * Nc + gc) = v;
      }
    }
  }
  if (STATS) {
    for (int o2 = 32; o2; o2 >>= 1) {
      s  += __shfl_down(s,  o2, 64);
      s2 += __shfl_down(s2, o2, 64);
    }
    __shared__ float ps[8];
    if (lane == 0) { ps[wave] = s; ps[wave + 4] = s2; }
    __syncthreads();
    if (tid == 0) {
      int bid = blockIdx.y * gridDim.x + blockIdx.x;
      partials[2 * bid]     = ps[0] + ps[1] + ps[2] + ps[3];
      partials[2 * bid + 1] = ps[4] + ps[5] + ps[6] + ps[7];
    }
  }
}

extern "C" void kernel_launch(void* const* d_in, const int* in_sizes, int n_in,
                              void* d_out, int out_size, void* d_ws, size_t ws_size,
                              hipStream_t stream) {
  const float* x    = (const float*)d_in[0];
  const void*  edge = d_in[1];
  const float* Wl1  = (const float*)d_in[2];
  const float* bl1  = (const float*)d_in[3];
  const float* Wr1  = (const float*)d_in[4];
  const float* ln1w = (const float*)d_in[5];
  const float* ln1b = (const float*)d_in[6];
  const float* W1   = (const float*)d_in[7];
  const float* b1   = (const float*)d_in[8];
  const float* W2   = (const float*)d_in[9];
  const float* b2   = (const float*)d_in[10];
  const float* Wl2  = (const float*)d_in[11];
  const float* bl2  = (const float*)d_in[12];
  const float* Wr2  = (const float*)d_in[13];
  const float* ln2w = (const float*)d_in[14];
  const float* ln2b = (const float*)d_in[15];
  const float* W3   = (const float*)d_in[16];
  const float* b3   = (const float*)d_in[17];
  const float* W4   = (const float*)d_in[18];
  const float* b4   = (const float*)d_in[19];
  float* out = (float*)d_out;

  char* wsp = (char*)d_ws;
  size_t o = 0;
  auto alloc = [&](size_t bytes) -> void* {
    void* p = wsp + o;
    o = (o + bytes + 255) & ~(size_t)255;
    return p;
  };
  // Footprint ~88 MB (< R2's proven-safe 94.6 MB).
  int*   flag   = (int*)alloc(4);
  int*   bcnt   = (int*)alloc(NBUCK * 4);
  int*   bstart = (int*)alloc((NBUCK + 1) * 4);
  int*   bcur   = (int*)alloc(NBUCK * 4);
  int*   offs   = (int*)alloc((size_t)(NN + 1) * 4);
  int*   csr    = (int*)alloc((size_t)EE * 4);
  long long* staging = (long long*)alloc((size_t)EE * 8);   // 6.4 MB
  float* stats  = (float*)alloc(32);
  float* cbias  = (float*)alloc(256 * 4);
  float* pb1    = (float*)alloc(782 * 2 * 4);
  float* pb2    = (float*)alloc(3128 * 2 * 4);
  short* wc1T   = (short*)alloc(256 * 256 * 2);
  short* w1T    = (short*)alloc(512 * 256 * 2);
  short* w2T    = (short*)alloc(256 * 512 * 2);
  short* wlr2T  = (short*)alloc(256 * 256 * 2);
  short* w3T    = (short*)alloc(256 * 128 * 2);
  short* w4T    = (short*)alloc(128 * 256 * 2);
  char*  bufB   = (char*)alloc((size_t)MPAD * 512);    // 25.6 MB
  char*  bufA   = (char*)alloc((size_t)MPAD * 1024);   // 51.2 MB

  const size_t Q = (size_t)MPAD * 256;   // 12.8 MB quarter of bufA
  short* xbf = (short*)bufA;
  short* h1  = (short*)bufA;
  short* h_b = (short*)bufA;
  short* p2  = (short*)bufA;
  short* r2  = (short*)(bufA + Q);
  short* a2  = (short*)(bufA + 2 * Q);
  short* h_d = (short*)(bufA + 3 * Q);
  short* h_e = (short*)bufA;
  short* h_f = (short*)(bufA + Q);
  short* hcat1 = (short*)bufB;
  short* h_a   = (short*)bufB;
  short* h_c   = (short*)bufB;

  hipMemsetAsync(bcnt, 0, NBUCK * 4, stream);
  detect_kernel<<<1, 256, 0, stream>>>((const unsigned*)edge, flag);
  bin_count<<<NBUCK, 256, 0, stream>>>(edge, flag, bcnt);
  bin_scan<<<1, 256, 0, stream>>>(bcnt, bstart, bcur);
  bin_scatter<<<NBUCK, 256, 0, stream>>>(edge, flag, bcur, staging);
  bucket_csr<<<NBUCK, 256, 0, stream>>>(bstart, staging, offs, csr);

  xcast_kernel<<<(NN * 128 / 8 + 255) / 256, 256, 0, stream>>>(x, xbf);
  prep_all<<<1792, 256, 0, stream>>>(Wl1, Wr1, W1, W2, Wl2, Wr2, W3, W4,
                                     wc1T, w1T, w2T, wlr2T, w3T, w4T);
  prep_bias<<<1, 256, 0, stream>>>(bl2, cbias);

  // ---- layer 1 ----
  agg_mean<1><<<MPAD / 4, 256, 0, stream>>>(xbf, offs, csr, hcat1);
  gemm_bt<0, 1, 1, 1, 0><<<dim3(2, MPAD / 128), 256, 0, stream>>>(
      hcat1, wc1T, bl1, nullptr, h1, nullptr, pb1, 256, 256, NN);
  reduce_stats<<<1, 256, 0, stream>>>(pb1, 782, stats);
  ln_apply<<<(MPAD * 256 / 4 + 255) / 256, 256, 0, stream>>>(
      h1, stats, ln1w, ln1b, h_a, NN * 256, MPAD * 256, 256, 1.f / (NN * 256.f));
  gemm_bt<1, 1, 0, 0, 0><<<dim3(4, MPAD / 128), 256, 0, stream>>>(
      h_a, w1T, b1, nullptr, h_b, nullptr, nullptr, 512, 256, MPAD);
  gemm_bt<1, 1, 0, 0, 0><<<dim3(2, MPAD / 128), 256, 0, stream>>>(
      h_b, w2T, b2, nullptr, h_c, nullptr, nullptr, 256, 512, MPAD);

  // ---- layer 2: fused dual projection, then aggregate ----
  gemm_bt<0, 1, 0, 0, 1><<<dim3(2, MPAD / 128), 256, 0, stream>>>(
      h_c, wlr2T, cbias, nullptr, p2, r2, nullptr, 256, 256, MPAD);
  agg_mean<0><<<MPAD / 4, 256, 0, stream>>>(p2, offs, csr, a2);
  add_stats<<<MPAD * 128 / 8 / 256, 256, 0, stream>>>(r2, a2, h_d, pb2);
  reduce_stats<<<1, 256, 0, stream>>>(pb2, 3128, stats + 2);
  ln_apply<<<(MPAD * 128 / 4 + 255) / 256, 256, 0, stream>>>(
      h_d, stats + 2, ln2w, ln2b, h_e, NN * 128, MPAD * 128, 128, 1.f / (NN * 128.f));
  gemm_bt<1, 1, 0, 0, 0><<<dim3(2, MPAD / 128), 256, 0, stream>>>(
      h_e, w3T, b3, nullptr, h_f, nullptr, nullptr, 256, 128, MPAD);
  gemm_bt<0, 0, 1, 0, 0><<<dim3(1, MPAD / 128), 256, 0, stream>>>(
      h_f, w4T, b4, out, nullptr, nullptr, nullptr, 128, 256, NN);
}

// Round 10
// 381.429 us; speedup vs baseline: 1.4430x; 1.0566x over previous
//
#include <hip/hip_runtime.h>

#define NN   50000
#define EE   800000
#define MPAD 50048   // 391 * 128
#define NBUCK 196    // dst>>8 buckets (256 nodes each)

typedef __bf16 bf16x8 __attribute__((ext_vector_type(8)));
typedef float  vfloat4 __attribute__((ext_vector_type(4)));
typedef short  vshort4 __attribute__((ext_vector_type(4)));
typedef short  vshort8 __attribute__((ext_vector_type(8)));

__device__ __forceinline__ short f2bf(float f) {
  union { float f; unsigned u; } v; v.f = f;
  unsigned r = v.u + 0x7FFFu + ((v.u >> 16) & 1u);   // RNE
  return (short)(r >> 16);
}
__device__ __forceinline__ float bf2f(short h) {
  union { unsigned u; float f; } v; v.u = ((unsigned)(unsigned short)h) << 16;
  return v.f;
}

__device__ __forceinline__ void load_lds16(const short* g, short* l) {
  __builtin_amdgcn_global_load_lds(
      (__attribute__((address_space(1))) void*)(void*)g,
      (__attribute__((address_space(3))) void*)(void*)l, 16, 0, 0);
}

// ---------------- edge dtype detect (int64 vs int32) ----------------
__global__ __launch_bounds__(256) void detect_kernel(const unsigned* __restrict__ e,
                                                     int* __restrict__ flag) {
  unsigned v = 0;
  for (int i = threadIdx.x; i < 2048; i += 256) v |= e[2 * i + 1];
  for (int o = 32; o; o >>= 1) v |= (unsigned)__shfl_down((int)v, o, 64);
  __shared__ unsigned r[4];
  if ((threadIdx.x & 63) == 0) r[threadIdx.x >> 6] = v;
  __syncthreads();
  if (threadIdx.x == 0) flag[0] = ((r[0] | r[1] | r[2] | r[3]) == 0) ? 1 : 0;
}

// ---------------- CSR build: 2-level bucket sort (R8: kills 19x write amp) --
__global__ __launch_bounds__(256) void bin_count(const void* __restrict__ edges,
                                                 const int* __restrict__ flag,
                                                 int* __restrict__ bcnt) {
  __shared__ int h[NBUCK];
  int t = threadIdx.x;
  for (int i = t; i < NBUCK; i += 256) h[i] = 0;
  __syncthreads();
  const int per = (EE + NBUCK - 1) / NBUCK;
  int lo = blockIdx.x * per, hi = lo + per;
  if (hi > EE) hi = EE;
  int fl = flag[0];
  for (int e = lo + t; e < hi; e += 256) {
    int dv = fl ? (int)((const long long*)edges)[EE + e] : ((const int*)edges)[EE + e];
    atomicAdd(&h[dv >> 8], 1);
  }
  __syncthreads();
  for (int i = t; i < NBUCK; i += 256)
    if (h[i]) atomicAdd(&bcnt[i], h[i]);
}

__global__ __launch_bounds__(256) void bin_scan(const int* __restrict__ bcnt,
                                                int* __restrict__ bstart,
                                                int* __restrict__ bcur) {
  __shared__ int tmp[256];
  int t = threadIdx.x;
  int v = (t < NBUCK) ? bcnt[t] : 0;
  tmp[t] = v;
  __syncthreads();
  int acc = v;
  for (int d = 1; d < 256; d <<= 1) {
    int u = (t >= d) ? tmp[t - d] : 0;
    __syncthreads();
    acc += u;
    tmp[t] = acc;
    __syncthreads();
  }
  int excl = acc - v;
  if (t < NBUCK) { bstart[t] = excl; bcur[t] = excl; }
  if (t == NBUCK - 1) bstart[NBUCK] = excl + v;   // == EE
}

__global__ __launch_bounds__(256) void bin_scatter(const void* __restrict__ edges,
                                                   const int* __restrict__ flag,
                                                   int* __restrict__ bcur,
                                                   long long* __restrict__ staging) {
  __shared__ int h[NBUCK];
  __shared__ int base[NBUCK];
  int t = threadIdx.x;
  for (int i = t; i < NBUCK; i += 256) h[i] = 0;
  __syncthreads();
  const int per = (EE + NBUCK - 1) / NBUCK;
  int lo = blockIdx.x * per, hi = lo + per;
  if (hi > EE) hi = EE;
  int fl = flag[0];
  for (int e = lo + t; e < hi; e += 256) {
    int dv = fl ? (int)((const long long*)edges)[EE + e] : ((const int*)edges)[EE + e];
    atomicAdd(&h[dv >> 8], 1);
  }
  __syncthreads();
  for (int i = t; i < NBUCK; i += 256) {
    int c = h[i];
    base[i] = c ? atomicAdd(&bcur[i], c) : 0;
    h[i] = 0;
  }
  __syncthreads();
  for (int e = lo + t; e < hi; e += 256) {
    int sv, dv;
    if (fl) { sv = (int)((const long long*)edges)[e]; dv = (int)((const long long*)edges)[EE + e]; }
    else    { sv = ((const int*)edges)[e];            dv = ((const int*)edges)[EE + e]; }
    int b = dv >> 8;
    int r = atomicAdd(&h[b], 1);
    staging[base[b] + r] = ((long long)sv << 32) | (unsigned)dv;
  }
}

__global__ __launch_bounds__(256) void bucket_csr(const int* __restrict__ bstart,
                                                  const long long* __restrict__ staging,
                                                  int* __restrict__ offs,
                                                  int* __restrict__ csr) {
  int b = blockIdx.x, t = threadIdx.x;
  int n0 = b << 8;
  int s0 = bstart[b], s1 = bstart[b + 1];
  __shared__ int cnt[256], tmp[256], cur[256];
  cnt[t] = 0;
  __syncthreads();
  for (int i = s0 + t; i < s1; i += 256)
    atomicAdd(&cnt[((int)(staging[i] & 0xffffffffLL)) - n0], 1);
  __syncthreads();
  int v = cnt[t];
  tmp[t] = v;
  __syncthreads();
  int acc = v;
  for (int d = 1; d < 256; d <<= 1) {
    int u = (t >= d) ? tmp[t - d] : 0;
    __syncthreads();
    acc += u;
    tmp[t] = acc;
    __syncthreads();
  }
  int excl = acc - v;
  int node = n0 + t;
  if (node < NN) offs[node] = s0 + excl;
  cur[t] = s0 + excl;
  __syncthreads();
  for (int i = s0 + t; i < s1; i += 256) {
    long long pk = staging[i];
    int dv = (int)(pk & 0xffffffffLL);
    int sv = (int)(pk >> 32);
    int p = atomicAdd(&cur[dv - n0], 1);
    csr[p] = sv;
  }
  if (b == 0 && t == 0) offs[NN] = EE;
}

// ---------------- x -> bf16 cast (NN x 128) ----------------
__global__ __launch_bounds__(256) void xcast_kernel(const float* __restrict__ x,
                                                    short* __restrict__ xbf) {
  int i = blockIdx.x * 256 + threadIdx.x;
  if (i >= NN * 128 / 8) return;
  vfloat4 v0 = *(const vfloat4*)(x + (size_t)i * 8);
  vfloat4 v1 = *(const vfloat4*)(x + (size_t)i * 8 + 4);
  vshort8 o;
  o[0] = f2bf(v0.x); o[1] = f2bf(v0.y); o[2] = f2bf(v0.z); o[3] = f2bf(v0.w);
  o[4] = f2bf(v1.x); o[5] = f2bf(v1.y); o[6] = f2bf(v1.z); o[7] = f2bf(v1.w);
  *(vshort8*)(xbf + (size_t)i * 8) = o;
}

// ---------------- all weight preps in one launch ----------------
__global__ __launch_bounds__(256) void prep_all(
    const float* __restrict__ Wl1, const float* __restrict__ Wr1,
    const float* __restrict__ W1,  const float* __restrict__ W2,
    const float* __restrict__ Wl2, const float* __restrict__ Wr2,
    const float* __restrict__ W3,  const float* __restrict__ W4,
    short* __restrict__ wc1T, short* __restrict__ w1T, short* __restrict__ w2T,
    short* __restrict__ wlr2T, short* __restrict__ w3T, short* __restrict__ w4T) {
  int b = blockIdx.x;
  if (b >= 1280 && b < 1536) {
    int idx = (b - 1280) * 256 + threadIdx.x;
    int n = idx >> 8, k = idx & 255;
    float v = (n < 128) ? Wl2[(size_t)k * 128 + n] : Wr2[(size_t)k * 128 + (n - 128)];
    wlr2T[idx] = f2bf(v);
    return;
  }
  const float *s0, *s1; short* dst; int K0, logK, Nc, base;
  if      (b <  256) { s0=Wl1; s1=Wr1; dst=wc1T; K0=128; logK=8; Nc=256; base=0;    }
  else if (b <  768) { s0=W1;  s1=W1;  dst=w1T;  K0=256; logK=8; Nc=512; base=256;  }
  else if (b < 1280) { s0=W2;  s1=W2;  dst=w2T;  K0=512; logK=9; Nc=256; base=768;  }
  else if (b < 1664) { s0=W3;  s1=W3;  dst=w3T;  K0=128; logK=7; Nc=256; base=1536; }
  else               { s0=W4;  s1=W4;  dst=w4T;  K0=256; logK=8; Nc=128; base=1664; }
  int idx = (b - base) * 256 + threadIdx.x;
  int n = idx >> logK, k = idx & ((1 << logK) - 1);
  float v = (k < K0) ? s0[(size_t)k * Nc + n] : s1[(size_t)(k - K0) * Nc + n];
  dst[idx] = f2bf(v);
}

// cbias[256] = [0 x128 | bl2]
__global__ __launch_bounds__(256) void prep_bias(const float* __restrict__ bl2,
                                                 float* __restrict__ cbias) {
  int t = threadIdx.x;
  cbias[t] = (t < 128) ? 0.f : bl2[t - 128];
}

// ---------------- partial-sum reduce (1 block) ----------------
__global__ __launch_bounds__(256) void reduce_stats(const float* __restrict__ part,
                                                    int n, float* __restrict__ out) {
  float s = 0.f, s2 = 0.f;
  for (int i = threadIdx.x; i < n; i += 256) { s += part[2 * i]; s2 += part[2 * i + 1]; }
  for (int o = 32; o; o >>= 1) {
    s  += __shfl_down(s,  o, 64);
    s2 += __shfl_down(s2, o, 64);
  }
  __shared__ float ps[8];
  int lane = threadIdx.x & 63, wv = threadIdx.x >> 6;
  if (lane == 0) { ps[wv] = s; ps[wv + 4] = s2; }
  __syncthreads();
  if (threadIdx.x == 0) {
    out[0] = ps[0] + ps[1] + ps[2] + ps[3];
    out[1] = ps[4] + ps[5] + ps[6] + ps[7];
  }
}

// ---------------- mean aggregation over 128-elem bf16 rows ----------------
template<int CONCAT>
__global__ __launch_bounds__(256) void agg_mean(const short* __restrict__ src,
                                                const int* __restrict__ offs,
                                                const int* __restrict__ csr,
                                                short* __restrict__ dst) {
  int node = blockIdx.x * 4 + (threadIdx.x >> 6);
  int lane = threadIdx.x & 63;
  if (node >= MPAD) return;
  short* row = dst + (size_t)node * (CONCAT ? 256 : 128);
  if (node >= NN) {
    if (CONCAT) *(vshort4*)(row + lane * 4) = (vshort4){0, 0, 0, 0};
    else if (lane < 32) *(vshort4*)(row + lane * 4) = (vshort4){0, 0, 0, 0};
    return;
  }
  int g = lane >> 4, sub = lane & 15;
  int e0 = offs[node], e1 = offs[node + 1];
  float a0[8] = {0, 0, 0, 0, 0, 0, 0, 0};
  float a1[8] = {0, 0, 0, 0, 0, 0, 0, 0};
  int e = e0;
  while (e < e1) {                         // wave-uniform
    int cnt = e1 - e; if (cnt > 64) cnt = 64;
    int myidx = (lane < cnt) ? csr[e + lane] : 0;
    for (int i = 0; i < cnt; i += 8) {     // wave-uniform bound (R4 lesson)
      int p0 = g + i;
      int p1 = g + i + 4;
      int s0 = __shfl(myidx, p0, 64);      // full wave active
      int s1 = __shfl(myidx, p1, 64);
      if (p0 < cnt) {
        vshort8 v0 = *(const vshort8*)(src + (size_t)s0 * 128 + sub * 8);
#pragma unroll
        for (int j = 0; j < 8; j++) a0[j] += bf2f(v0[j]);
      }
      if (p1 < cnt) {
        vshort8 v1 = *(const vshort8*)(src + (size_t)s1 * 128 + sub * 8);
#pragma unroll
        for (int j = 0; j < 8; j++) a1[j] += bf2f(v1[j]);
      }
    }
    e += cnt;
  }
#pragma unroll
  for (int j = 0; j < 8; j++) {
    a0[j] += a1[j];
    a0[j] += __shfl_down(a0[j], 32, 64);
    a0[j] += __shfl_down(a0[j], 16, 64);
  }
  float inv = (e1 > e0) ? 1.f / (float)(e1 - e0) : 0.f;
  if (g == 0) {
    vshort8 o;
#pragma unroll
    for (int j = 0; j < 8; j++) o[j] = f2bf(a0[j] * inv);
    *(vshort8*)(row + sub * 8) = o;
  } else if (CONCAT && g == 1) {
    *(vshort8*)(row + 128 + sub * 8) = *(const vshort8*)(src + (size_t)node * 128 + sub * 8);
  }
}

// ---------------- h_d = r2 + a2 (bf16), per-block stats partials ------------
__global__ __launch_bounds__(256) void add_stats(const short* __restrict__ r2,
                                                 const short* __restrict__ a2,
                                                 short* __restrict__ h_d,
                                                 float* __restrict__ partials) {
  int i = blockIdx.x * 256 + threadIdx.x;
  const int tot8 = MPAD * 128 / 8, real8 = NN * 128 / 8;
  float s = 0.f, s2 = 0.f;
  if (i < tot8) {
    if (i >= real8) {
      *(vshort8*)(h_d + (size_t)i * 8) = (vshort8){0,0,0,0,0,0,0,0};
    } else {
      vshort8 rv = *(const vshort8*)(r2 + (size_t)i * 8);
      vshort8 av = *(const vshort8*)(a2 + (size_t)i * 8);
      vshort8 o;
#pragma unroll
      for (int j = 0; j < 8; j++) {
        float v = bf2f(rv[j]) + bf2f(av[j]);
        s += v; s2 += v * v;
        o[j] = f2bf(v);
      }
      *(vshort8*)(h_d + (size_t)i * 8) = o;
    }
  }
  int lane = threadIdx.x & 63, wave = threadIdx.x >> 6;
  for (int o2 = 32; o2; o2 >>= 1) {
    s  += __shfl_down(s,  o2, 64);
    s2 += __shfl_down(s2, o2, 64);
  }
  __shared__ float ps[8];
  if (lane == 0) { ps[wave] = s; ps[wave + 4] = s2; }
  __syncthreads();
  if (threadIdx.x == 0) {
    partials[2 * blockIdx.x]     = ps[0] + ps[1] + ps[2] + ps[3];   // no atomics (R7)
    partials[2 * blockIdx.x + 1] = ps[4] + ps[5] + ps[6] + ps[7];
  }
}

// ---------------- graph LayerNorm apply (bf16 in) ----------------
__global__ __launch_bounds__(256) void ln_apply(const short* __restrict__ h,
                                                const float* __restrict__ stats,
                                                const float* __restrict__ w,
                                                const float* __restrict__ b,
                                                short* __restrict__ out,
                                                int realElems, int totElems, int F,
                                                float invCount) {
  int base = (blockIdx.x * blockDim.x + threadIdx.x) * 4;
  if (base >= totElems) return;
  if (base >= realElems) { *(vshort4*)(out + base) = (vshort4){0,0,0,0}; return; }
  float mu  = stats[0] * invCount;
  float var = stats[1] * invCount - mu * mu;
  float rs  = rsqrtf(var + 1e-5f);
  int col = base % F;
  vshort4 hv = *(const vshort4*)(h + base);
  vshort4 o;
  o.x = f2bf(fmaxf((bf2f(hv.x) - mu) * rs * w[col]     + b[col],     0.f));
  o.y = f2bf(fmaxf((bf2f(hv.y) - mu) * rs * w[col + 1] + b[col + 1], 0.f));
  o.z = f2bf(fmaxf((bf2f(hv.z) - mu) * rs * w[col + 2] + b[col + 2], 0.f));
  o.w = f2bf(fmaxf((bf2f(hv.w) - mu) * rs * w[col + 3] + b[col + 3], 0.f));
  *(vshort4*)(out + base) = o;
}

// ---------------- standalone GEMM (gemm1 + split projection) --------------
// BK=64, XOR-swizzled LDS, swapped mfma operands, vectorized epilogue.
template<int RELU, int OUTBF, int BOUND, int STATS, int SPLIT>
__global__ __launch_bounds__(256) void gemm_bt(const short* __restrict__ A,
                                               const short* __restrict__ BT,
                                               const float* __restrict__ bias,
                                               float* __restrict__ Cf,
                                               short* __restrict__ Cb,
                                               short* __restrict__ Cb2,
                                               float* __restrict__ partials,
                                               int Nc, int K, int Mreal) {
  __shared__ short lsA[128 * 64];
  __shared__ short lsB[128 * 64];
  const int tid  = threadIdx.x;
  const int lane = tid & 63;
  const int wave = tid >> 6;
  const int wr   = (wave >> 1) << 6;
  const int wc   = (wave & 1) << 6;
  const int row0 = blockIdx.y << 7;
  const int col0 = blockIdx.x << 7;
  const int r16  = lane & 15;
  const int quad = lane >> 4;
  const int srow   = lane >> 3;
  const int schunk = lane & 7;
  const int sxoff  = ((schunk ^ srow) << 3);

  vfloat4 acc[4][4];
#pragma unroll
  for (int i = 0; i < 4; i++)
#pragma unroll
    for (int j = 0; j < 4; j++) acc[i][j] = (vfloat4){0.f, 0.f, 0.f, 0.f};

  for (int k0 = 0; k0 < K; k0 += 64) {
    __syncthreads();
#pragma unroll
    for (int t = 0; t < 4; t++) {
      int seg  = (wave << 2) + t;
      int trow = (seg << 3) + srow;
      load_lds16(A  + (size_t)(row0 + trow) * K + k0 + sxoff, lsA + (seg << 9) + lane * 8);
      load_lds16(BT + (size_t)(col0 + trow) * K + k0 + sxoff, lsB + (seg << 9) + lane * 8);
    }
    __syncthreads();
#pragma unroll
    for (int kk = 0; kk < 64; kk += 32) {
      int kf8 = (kk >> 3) + quad;
      bf16x8 af[4], bfr[4];
#pragma unroll
      for (int i = 0; i < 4; i++) {
        int r = wr + (i << 4) + r16;
        af[i] = *(const bf16x8*)(lsA + (r << 6) + ((kf8 ^ (r & 7)) << 3));
      }
#pragma unroll
      for (int j = 0; j < 4; j++) {
        int r = wc + (j << 4) + r16;
        bfr[j] = *(const bf16x8*)(lsB + (r << 6) + ((kf8 ^ (r & 7)) << 3));
      }
#pragma unroll
      for (int i = 0; i < 4; i++)
#pragma unroll
        for (int j = 0; j < 4; j++)
          acc[i][j] = __builtin_amdgcn_mfma_f32_16x16x32_bf16(bfr[j], af[i], acc[i][j], 0, 0, 0);
    }
  }

  float s = 0.f, s2 = 0.f;
#pragma unroll
  for (int i = 0; i < 4; i++) {
    int gr = row0 + wr + (i << 4) + r16;
    if (BOUND && gr >= Mreal) continue;
#pragma unroll
    for (int j = 0; j < 4; j++) {
      int gc = col0 + wc + (j << 4) + (quad << 2);
      vfloat4 bv = *(const vfloat4*)(bias + gc);
      vfloat4 v;
#pragma unroll
      for (int p = 0; p < 4; p++) {
        float t = acc[i][j][p] + bv[p];
        if (STATS) { s += t; s2 += t * t; }
        if (RELU) t = fmaxf(t, 0.f);
        v[p] = t;
      }
      if (OUTBF) {
        vshort4 o;
#pragma unroll
        for (int p = 0; p < 4; p++) o[p] = f2bf(v[p]);
        if (SPLIT) {
          if (gc < 128) *(vshort4*)(Cb  + (size_t)gr * 128 + gc)       = o;
          else          *(vshort4*)(Cb2 + (size_t)gr * 128 + gc - 128) = o;
        } else {
          *(vshort4*)(Cb + (size_t)gr * Nc + gc) = o;
        }
      } else {
        *(vfloat4*)(Cf + (size_t)gr * Nc + gc) = v;
      }
    }
  }
  if (STATS) {
    for (int o2 = 32; o2; o2 >>= 1) {
      s  += __shfl_down(s,  o2, 64);
      s2 += __shfl_down(s2, o2, 64);
    }
    __shared__ float ps[8];
    if (lane == 0) { ps[wave] = s; ps[wave + 4] = s2; }
    __syncthreads();
    if (tid == 0) {
      int bid = blockIdx.y * gridDim.x + blockIdx.x;
      partials[2 * bid]     = ps[0] + ps[1] + ps[2] + ps[3];
      partials[2 * bid + 1] = ps[4] + ps[5] + ps[6] + ps[7];
    }
  }
}

// ---------------- fused back-to-back MLP GEMM pair -------------------------
// C2 = act2( act1(A @ B1 + bias1) @ B2 + bias2 )
// Per 128-row block: intermediate computed 128-col chunk at a time into
// 32 KB swizzled LDS (hmid), immediately consumed by phase-2 K-accumulation.
// Eliminates the HBM round trip of the intermediate (R9: 102 MB for W1W2).
// A:[MPAD][K1], B1T:[N1][K1], B2T:[N2][N1]. LDS 64 KB -> 2 blocks/CU.
template<int K1, int N1, int N2, int RELU2, int OUTBF, int BOUND>
__global__ __launch_bounds__(256, 2) void fused_mlp(
    const short* __restrict__ A,
    const short* __restrict__ B1T, const float* __restrict__ bias1,
    const short* __restrict__ B2T, const float* __restrict__ bias2,
    short* __restrict__ Cb, float* __restrict__ Cf, int Mreal) {
  constexpr int J2 = N2 / 32;     // col fragments per wave in phase 2
  __shared__ short hmid[128 * 128];   // 32 KB swizzled intermediate chunk
  __shared__ short stg[16384];        // 32 KB: lsA|lsB1 (ph1), lsB2 (ph2)
  short* lsA  = stg;
  short* lsB1 = stg + 8192;
  short* lsB2 = stg;
  const int tid  = threadIdx.x;
  const int lane = tid & 63;
  const int wave = tid >> 6;
  const int wr   = (wave >> 1) << 6;
  const int wc1  = (wave & 1) << 6;
  const int wc2  = (wave & 1) * (N2 / 2);
  const int row0 = blockIdx.x << 7;
  const int r16  = lane & 15;
  const int quad = lane >> 4;
  const int srow   = lane >> 3;
  const int schunk = lane & 7;
  const int sxoff  = ((schunk ^ srow) << 3);

  vfloat4 acc2[4][J2];
#pragma unroll
  for (int i = 0; i < 4; i++)
#pragma unroll
    for (int j = 0; j < J2; j++) acc2[i][j] = (vfloat4){0.f, 0.f, 0.f, 0.f};

#pragma unroll 1
  for (int cc = 0; cc < N1 / 128; cc++) {
    // ---- phase 1: hmid = act1(A @ B1[:, cc*128 : cc*128+128] + bias1) ----
    vfloat4 acc1[4][4];
#pragma unroll
    for (int i = 0; i < 4; i++)
#pragma unroll
      for (int j = 0; j < 4; j++) acc1[i][j] = (vfloat4){0.f, 0.f, 0.f, 0.f};
#pragma unroll 1
    for (int k0 = 0; k0 < K1; k0 += 64) {
      __syncthreads();
#pragma unroll
      for (int t = 0; t < 4; t++) {
        int seg  = (wave << 2) + t;
        int trow = (seg << 3) + srow;
        load_lds16(A   + (size_t)(row0 + trow) * K1 + k0 + sxoff,     lsA  + (seg << 9) + lane * 8);
        load_lds16(B1T + (size_t)(cc * 128 + trow) * K1 + k0 + sxoff, lsB1 + (seg << 9) + lane * 8);
      }
      __syncthreads();
#pragma unroll
      for (int kk = 0; kk < 64; kk += 32) {
        int kf8 = (kk >> 3) + quad;
        bf16x8 af[4], bfr[4];
#pragma unroll
        for (int i = 0; i < 4; i++) {
          int r = wr + (i << 4) + r16;
          af[i] = *(const bf16x8*)(lsA + (r << 6) + ((kf8 ^ (r & 7)) << 3));
        }
#pragma unroll
        for (int j = 0; j < 4; j++) {
          int r = wc1 + (j << 4) + r16;
          bfr[j] = *(const bf16x8*)(lsB1 + (r << 6) + ((kf8 ^ (r & 7)) << 3));
        }
#pragma unroll
        for (int i = 0; i < 4; i++)
#pragma unroll
          for (int j = 0; j < 4; j++)
            acc1[i][j] = __builtin_amdgcn_mfma_f32_16x16x32_bf16(bfr[j], af[i], acc1[i][j], 0, 0, 0);
      }
    }
    // phase-1 epilogue -> hmid (swizzled, bias + relu + bf16)
#pragma unroll
    for (int i = 0; i < 4; i++) {
      int rr = wr + (i << 4) + r16;
#pragma unroll
      for (int j = 0; j < 4; j++) {
        int ccol = wc1 + (j << 4) + (quad << 2);
        vfloat4 bv = *(const vfloat4*)(bias1 + cc * 128 + ccol);
        vshort4 o;
#pragma unroll
        for (int p = 0; p < 4; p++) o[p] = f2bf(fmaxf(acc1[i][j][p] + bv[p], 0.f));
        int c8 = ccol >> 3;
        *(vshort4*)(hmid + rr * 128 + ((c8 ^ (rr & 7)) << 3) + (quad & 1) * 4) = o;
      }
    }
    // ---- phase 2: acc2 += hmid @ B2[cc*128 : cc*128+128, :] ----
#pragma unroll 1
    for (int kk2 = 0; kk2 < 128; kk2 += 64) {
      __syncthreads();   // hmid visible; stg safe to overwrite
#pragma unroll
      for (int t = 0; t < N2 / 32; t++) {
        int seg  = wave * (N2 / 32) + t;
        int trow = (seg << 3) + srow;
        load_lds16(B2T + (size_t)trow * N1 + cc * 128 + kk2 + sxoff, lsB2 + (seg << 9) + lane * 8);
      }
      __syncthreads();
#pragma unroll
      for (int kk = 0; kk < 64; kk += 32) {
        int kf8l = (kk >> 3) + quad;
        int hc8  = ((kk2 + kk) >> 3) + quad;
        bf16x8 af2[4], bfr2[J2];
#pragma unroll
        for (int i = 0; i < 4; i++) {
          int rr = wr + (i << 4) + r16;
          af2[i] = *(const bf16x8*)(hmid + rr * 128 + ((hc8 ^ (rr & 7)) << 3));
        }
#pragma unroll
        for (int j = 0; j < J2; j++) {
          int r = wc2 + (j << 4) + r16;
          bfr2[j] = *(const bf16x8*)(lsB2 + (r << 6) + ((kf8l ^ (r & 7)) << 3));
        }
#pragma unroll
        for (int i = 0; i < 4; i++)
#pragma unroll
          for (int j = 0; j < J2; j++)
            acc2[i][j] = __builtin_amdgcn_mfma_f32_16x16x32_bf16(bfr2[j], af2[i], acc2[i][j], 0, 0, 0);
      }
    }
  }
  // ---- phase-2 epilogue ----
#pragma unroll
  for (int i = 0; i < 4; i++) {
    int gr = row0 + wr + (i << 4) + r16;
    if (BOUND && gr >= Mreal) continue;
#pragma unroll
    for (int j = 0; j < J2; j++) {
      int gc = wc2 + (j << 4) + (quad << 2);
      vfloat4 bv = *(const vfloat4*)(bias2 + gc);
      vfloat4 v;
#pragma unroll
      for (int p = 0; p < 4; p++) {
        float t = acc2[i][j][p] + bv[p];
        if (RELU2) t = fmaxf(t, 0.f);
        v[p] = t;
      }
      if (OUTBF) {
        vshort4 o;
#pragma unroll
        for (int p = 0; p < 4; p++) o[p] = f2bf(v[p]);
        *(vshort4*)(Cb + (size_t)gr * N2 + gc) = o;
      } else {
        *(vfloat4*)(Cf + (size_t)gr * N2 + gc) = v;
      }
    }
  }
}

extern "C" void kernel_launch(void* const* d_in, const int* in_sizes, int n_in,
                              void* d_out, int out_size, void* d_ws, size_t ws_size,
                              hipStream_t stream) {
  const float* x    = (const float*)d_in[0];
  const void*  edge = d_in[1];
  const float* Wl1  = (const float*)d_in[2];
  const float* bl1  = (const float*)d_in[3];
  const float* Wr1  = (const float*)d_in[4];
  const float* ln1w = (const float*)d_in[5];
  const float* ln1b = (const float*)d_in[6];
  const float* W1   = (const float*)d_in[7];
  const float* b1   = (const float*)d_in[8];
  const float* W2   = (const float*)d_in[9];
  const float* b2   = (const float*)d_in[10];
  const float* Wl2  = (const float*)d_in[11];
  const float* bl2  = (const float*)d_in[12];
  const float* Wr2  = (const float*)d_in[13];
  const float* ln2w = (const float*)d_in[14];
  const float* ln2b = (const float*)d_in[15];
  const float* W3   = (const float*)d_in[16];
  const float* b3   = (const float*)d_in[17];
  const float* W4   = (const float*)d_in[18];
  const float* b4   = (const float*)d_in[19];
  float* out = (float*)d_out;

  char* wsp = (char*)d_ws;
  size_t o = 0;
  auto alloc = [&](size_t bytes) -> void* {
    void* p = wsp + o;
    o = (o + bytes + 255) & ~(size_t)255;
    return p;
  };
  // Footprint ~88 MB (< R2's proven-safe 94.6 MB).
  int*   flag   = (int*)alloc(4);
  int*   bcnt   = (int*)alloc(NBUCK * 4);
  int*   bstart = (int*)alloc((NBUCK + 1) * 4);
  int*   bcur   = (int*)alloc(NBUCK * 4);
  int*   offs   = (int*)alloc((size_t)(NN + 1) * 4);
  int*   csr    = (int*)alloc((size_t)EE * 4);
  long long* staging = (long long*)alloc((size_t)EE * 8);
  float* stats  = (float*)alloc(32);
  float* cbias  = (float*)alloc(256 * 4);
  float* pb1    = (float*)alloc(782 * 2 * 4);
  float* pb2    = (float*)alloc(3128 * 2 * 4);
  short* wc1T   = (short*)alloc(256 * 256 * 2);
  short* w1T    = (short*)alloc(512 * 256 * 2);
  short* w2T    = (short*)alloc(256 * 512 * 2);
  short* wlr2T  = (short*)alloc(256 * 256 * 2);
  short* w3T    = (short*)alloc(256 * 128 * 2);
  short* w4T    = (short*)alloc(128 * 256 * 2);
  char*  bufB   = (char*)alloc((size_t)MPAD * 512);    // 25.6 MB
  char*  bufA   = (char*)alloc((size_t)MPAD * 1024);   // 51.2 MB

  const size_t Q = (size_t)MPAD * 256;   // 12.8 MB quarter of bufA
  // bufA: xbf@0 -> h1@0 -> h_c@0(25.6) | p2@2Q | r2@3Q -> h_d@0 -> h_e@Q
  // bufB: hcat1 -> h_a -> a2@0
  short* xbf = (short*)bufA;
  short* h1  = (short*)bufA;
  short* h_c = (short*)bufA;
  short* p2  = (short*)(bufA + 2 * Q);
  short* r2  = (short*)(bufA + 3 * Q);
  short* h_d = (short*)bufA;
  short* h_e = (short*)(bufA + Q);
  short* hcat1 = (short*)bufB;
  short* h_a   = (short*)bufB;
  short* a2    = (short*)bufB;

  hipMemsetAsync(bcnt, 0, NBUCK * 4, stream);
  detect_kernel<<<1, 256, 0, stream>>>((const unsigned*)edge, flag);
  bin_count<<<NBUCK, 256, 0, stream>>>(edge, flag, bcnt);
  bin_scan<<<1, 256, 0, stream>>>(bcnt, bstart, bcur);
  bin_scatter<<<NBUCK, 256, 0, stream>>>(edge, flag, bcur, staging);
  bucket_csr<<<NBUCK, 256, 0, stream>>>(bstart, staging, offs, csr);

  xcast_kernel<<<(NN * 128 / 8 + 255) / 256, 256, 0, stream>>>(x, xbf);
  prep_all<<<1792, 256, 0, stream>>>(Wl1, Wr1, W1, W2, Wl2, Wr2, W3, W4,
                                     wc1T, w1T, w2T, wlr2T, w3T, w4T);
  prep_bias<<<1, 256, 0, stream>>>(bl2, cbias);

  // ---- layer 1 ----
  agg_mean<1><<<MPAD / 4, 256, 0, stream>>>(xbf, offs, csr, hcat1);
  gemm_bt<0, 1, 1, 1, 0><<<dim3(2, MPAD / 128), 256, 0, stream>>>(
      hcat1, wc1T, bl1, nullptr, h1, nullptr, pb1, 256, 256, NN);
  reduce_stats<<<1, 256, 0, stream>>>(pb1, 782, stats);
  ln_apply<<<(MPAD * 256 / 4 + 255) / 256, 256, 0, stream>>>(
      h1, stats, ln1w, ln1b, h_a, NN * 256, MPAD * 256, 256, 1.f / (NN * 256.f));
  // fused W1+W2: h_a -> h_c (no h_b round trip)
  fused_mlp<256, 512, 256, 1, 1, 0><<<MPAD / 128, 256, 0, stream>>>(
      h_a, w1T, b1, w2T, b2, h_c, nullptr, MPAD);

  // ---- layer 2: fused dual projection, then aggregate ----
  gemm_bt<0, 1, 0, 0, 1><<<dim3(2, MPAD / 128), 256, 0, stream>>>(
      h_c, wlr2T, cbias, nullptr, p2, r2, nullptr, 256, 256, MPAD);
  agg_mean<0><<<MPAD / 4, 256, 0, stream>>>(p2, offs, csr, a2);
  add_stats<<<MPAD * 128 / 8 / 256, 256, 0, stream>>>(r2, a2, h_d, pb2);
  reduce_stats<<<1, 256, 0, stream>>>(pb2, 3128, stats + 2);
  ln_apply<<<(MPAD * 128 / 4 + 255) / 256, 256, 0, stream>>>(
      h_d, stats + 2, ln2w, ln2b, h_e, NN * 128, MPAD * 128, 128, 1.f / (NN * 128.f));
  // fused W3+W4: h_e -> out (no h_f round trip)
  fused_mlp<128, 256, 128, 0, 0, 1><<<MPAD / 128, 256, 0, stream>>>(
      h_e, w3T, b3, w4T, b4, nullptr, out, NN);
}